// Round 7
// baseline (376.920 us; speedup 1.0000x reference)
//
#include <hip/hip_runtime.h>
#include <hip/hip_bf16.h>
#include <stdint.h>

// ---- problem constants ----
constexpr int D  = 1024;
constexpr int H  = 16;
constexpr int DH = 64;
constexpr int B  = 4;
constexpr int S  = 2048;
constexpr int BS = B * S;          // 8192
constexpr int NQKV = 3 * D;        // 3072

typedef __attribute__((ext_vector_type(8))) short bf16x8;
typedef __attribute__((ext_vector_type(4))) float f32x4;
typedef __attribute__((ext_vector_type(16))) float f32x16;
typedef __attribute__((ext_vector_type(4))) unsigned short us4;
typedef __attribute__((ext_vector_type(4))) unsigned int u32x4;
typedef unsigned short ushort_t;

using gu32 = __attribute__((address_space(1))) unsigned int;
using lu32 = __attribute__((address_space(3))) unsigned int;

__device__ __forceinline__ void gload_lds16(const void* g, void* l) {
  __builtin_amdgcn_global_load_lds((gu32*)g, (lu32*)l, 16, 0, 0);
}

__device__ __forceinline__ ushort_t f2bf(float f) {
  uint32_t u = __builtin_bit_cast(uint32_t, f);
  u += 0x7FFFu + ((u >> 16) & 1u);
  return (ushort_t)(u >> 16);
}

// packed f32x2 -> bf16x2 (src0 -> low 16, src1 -> high 16)
__device__ __forceinline__ unsigned cvtpk(float lo, float hi) {
  unsigned r;
  asm("v_cvt_pk_bf16_f32 %0, %1, %2" : "=v"(r) : "v"(lo), "v"(hi));
  return r;
}

// Cross-half exchange: lo-lane keeps w0,w1, gets other half's w0,w1 into w2,w3;
// hi-lane keeps w2,w3 (into w2,w3), gets other half's w2,w3 into w0,w1.
__device__ __forceinline__ void xch4(unsigned& w0, unsigned& w1,
                                     unsigned& w2, unsigned& w3, int hi) {
  unsigned sx = hi ? w0 : w2;               // what this lane sends
  unsigned sy = hi ? w1 : w3;
  sx = (unsigned)__shfl_xor((int)sx, 32, 64);
  sy = (unsigned)__shfl_xor((int)sy, 32, 64);
  if (hi) { w0 = sx; w1 = sy; } else { w2 = sx; w3 = sy; }
}

// ---------------- conversion kernels ----------------
__global__ __launch_bounds__(256) void k_conv_x(const float* __restrict__ x,
                                                ushort_t* __restrict__ xb) {
  int i = (blockIdx.x * 256 + threadIdx.x) * 4;
  float4 v = *(const float4*)(x + i);
  us4 o;
  o[0] = f2bf(v.x); o[1] = f2bf(v.y); o[2] = f2bf(v.z); o[3] = f2bf(v.w);
  *(us4*)(xb + i) = o;
}

// Wcat_t [3072][1024] bf16: row c -> (Wq|Wk|Wv)[h, d, e] with h=cl>>6, e=cl&63
__global__ __launch_bounds__(256) void k_conv_w(const float* __restrict__ Wq,
                                                const float* __restrict__ Wk,
                                                const float* __restrict__ Wv,
                                                ushort_t* __restrict__ wt) {
  int idx = blockIdx.x * 256 + threadIdx.x;   // 3072*1024
  int c = idx >> 10, d = idx & 1023;
  int cl = c & 1023;
  int hh = cl >> 6, e = cl & 63;
  const float* src = (c < 1024) ? Wq : ((c < 2048) ? Wk : Wv);
  wt[idx] = f2bf(src[(hh * D + d) * DH + e]);
}

// Wo_t [1024][1024] bf16: wot[c][d] = Wo[d][c]
__global__ __launch_bounds__(256) void k_conv_wo(const float* __restrict__ Wo,
                                                 ushort_t* __restrict__ wot) {
  int idx = blockIdx.x * 256 + threadIdx.x;   // 1024*1024
  int c = idx >> 10, d = idx & 1023;
  wot[idx] = f2bf(Wo[d * D + c]);
}

// ---- 256x256 GEMM core: 8 waves (2M x 4N), BK=32, 4-buffer counted-vmcnt pipeline ----
// K fixed = 1024 (32 tiles). A [M][1024], Bt [N][1024] bf16 row-major (2048B rows).
// LDS buffer (32KB): A-half rows 0-127 [0,8K) / rows 128-255 [8K,16K); B same at +16K.
// Rows are 64B; bank = (row&1)*16banks ^ chunk -> swizzle ch ^= (row>>1)&3 gives
// 2 lanes/bank (free, m136). Applied both-sides: inverse-swizzled global source
// (gload_lds dest stays linear) + swizzled ds_read address.
__device__ __forceinline__ void gemm_core_256(const ushort_t* __restrict__ A,
                                              const ushort_t* __restrict__ Bt,
                                              int m0, int n0,
                                              f32x4 acc[8][4], char* lds) {
  const int t = threadIdx.x;
  const int lane = t & 63, w = t >> 6;
  const int wm = w >> 2, wn = w & 3;
  const int lrow = lane & 15;
  const int chx = (((lane >> 4) ^ ((lrow >> 1) & 3)) << 4);

#pragma unroll
  for (int mi = 0; mi < 8; mi++)
#pragma unroll
    for (int ni = 0; ni < 4; ni++) acc[mi][ni] = f32x4{0.f, 0.f, 0.f, 0.f};

  // staging source: dest linear offset o=(j*512+t)*16 -> row=j*128+(t>>2), chunk=t&3;
  // source chunk = (t&3) ^ ((row>>1)&3)  (j*128 doesn't affect (row>>1)&3)
  const int prow = t >> 2;
  const int sw16 = (((t & 3) ^ ((prow >> 1) & 3)) << 4);
  const char* sA0 = (const char*)A  + (size_t)(m0 + prow) * 2048 + sw16;
  const char* sB0 = (const char*)Bt + (size_t)(n0 + prow) * 2048 + sw16;

  auto STAGE = [&](int kt) {
    char* bb = lds + (kt & 3) * 32768;
    const size_t ko = (size_t)kt * 64;
    gload_lds16(sA0 + ko,               bb + w * 1024);
    gload_lds16(sA0 + 128 * 2048 + ko,  bb + 8192 + w * 1024);
    gload_lds16(sB0 + ko,               bb + 16384 + w * 1024);
    gload_lds16(sB0 + 128 * 2048 + ko,  bb + 24576 + w * 1024);
  };

  STAGE(0); STAGE(1); STAGE(2);          // 12 VMEM ops in flight

  for (int kt = 0; kt < 32; ++kt) {
    // wait tile kt's 4 loads (oldest); kt+1,kt+2 stay in flight (T4: never drain-to-0)
    asm volatile("s_waitcnt vmcnt(8)" ::: "memory");
    __builtin_amdgcn_sched_barrier(0);
    __builtin_amdgcn_s_barrier();        // raw barrier: no implicit vmcnt(0) drain
    __builtin_amdgcn_sched_barrier(0);
    if (kt + 3 < 32) STAGE(kt + 3);      // overwrites buf[(kt-1)&3]: safe, all waves
                                         // finished its ds_reads before the barrier
    const char* bb = lds + (kt & 3) * 32768;
    const char* aB = bb + wm * 8192 + lrow * 64 + chx;
    const char* bB = bb + 16384 + wn * 4096 + lrow * 64 + chx;
    bf16x8 af[8], bf[4];
#pragma unroll
    for (int mi = 0; mi < 8; mi++) af[mi] = *(const bf16x8*)(aB + mi * 1024);
#pragma unroll
    for (int ni = 0; ni < 4; ni++) bf[ni] = *(const bf16x8*)(bB + ni * 1024);
    __builtin_amdgcn_s_setprio(1);
#pragma unroll
    for (int mi = 0; mi < 8; mi++)
#pragma unroll
      for (int ni = 0; ni < 4; ni++)
        acc[mi][ni] = __builtin_amdgcn_mfma_f32_16x16x32_bf16(af[mi], bf[ni], acc[mi][ni], 0, 0, 0);
    __builtin_amdgcn_s_setprio(0);
  }
}

// QKV GEMM 256^2: grid 12x32=384 (XCD-swizzled); epilogue bias + scatter
__global__ __launch_bounds__(512, 2) void k_qkv_gemm(const ushort_t* __restrict__ xb,
                                                     const ushort_t* __restrict__ wt,
                                                     const float* __restrict__ bq,
                                                     const float* __restrict__ bk,
                                                     const float* __restrict__ bv,
                                                     ushort_t* __restrict__ q_ws,
                                                     ushort_t* __restrict__ k_ws,
                                                     ushort_t* __restrict__ vT_ws) {
  __shared__ __align__(16) char lds[4][32768];
  const int bid = blockIdx.x;
  const int wg = (bid & 7) * 48 + (bid >> 3);   // 384 % 8 == 0: bijective
  const int tm = wg / 12, tn = wg - tm * 12;
  const int m0 = tm * 256, n0 = tn * 256;
  f32x4 acc[8][4];
  gemm_core_256(xb, wt, m0, n0, acc, &lds[0][0]);

  constexpr float QSC = 0.18033688011112042f;  // 0.125 * log2(e)
  const int t = threadIdx.x, lane = t & 63, w = t >> 6;
  const int wm = w >> 2, wn = w & 3;
  const int lrow = lane & 15, lgrp = lane >> 4;
#pragma unroll
  for (int mi = 0; mi < 8; mi++) {
    int rbase = m0 + wm * 128 + mi * 16 + lgrp * 4;
#pragma unroll
    for (int ni = 0; ni < 4; ni++) {
      int c = n0 + wn * 64 + ni * 16 + lrow;
      int which = c >> 10, cl = c & 1023;
      int hh = cl >> 6, e = cl & 63;
#pragma unroll
      for (int i = 0; i < 4; i++) {
        int r = rbase + i;
        int bb = r >> 11, ss = r & 2047;
        float v = acc[mi][ni][i];
        if (which == 0)      q_ws[((bb * H + hh) * S + ss) * 64 + e] = f2bf((v + bq[cl]) * QSC);
        else if (which == 1) k_ws[((bb * H + hh) * S + ss) * 64 + e] = f2bf(v + bk[cl]);
        else                 vT_ws[((bb * H + hh) * 64 + e) * S + ss] = f2bf(v + bv[cl]);
      }
    }
  }
}

// Output GEMM 256^2: z[8192,1024] = attn_bf @ wot^T + bo (fp32), grid 4x32=128
__global__ __launch_bounds__(512, 2) void k_out_gemm(const ushort_t* __restrict__ attn_bf,
                                                     const ushort_t* __restrict__ wot,
                                                     const float* __restrict__ bo,
                                                     float* __restrict__ z) {
  __shared__ __align__(16) char lds[4][32768];
  const int bid = blockIdx.x;
  const int wg = (bid & 7) * 16 + (bid >> 3);   // 128 % 8 == 0: bijective
  const int tm = wg >> 2, tn = wg & 3;
  const int m0 = tm * 256, n0 = tn * 256;
  f32x4 acc[8][4];
  gemm_core_256(attn_bf, wot, m0, n0, acc, &lds[0][0]);

  const int t = threadIdx.x, lane = t & 63, w = t >> 6;
  const int wm = w >> 2, wn = w & 3;
  const int lrow = lane & 15, lgrp = lane >> 4;
#pragma unroll
  for (int mi = 0; mi < 8; mi++) {
    int rbase = m0 + wm * 128 + mi * 16 + lgrp * 4;
#pragma unroll
    for (int ni = 0; ni < 4; ni++) {
      int c = n0 + wn * 64 + ni * 16 + lrow;
#pragma unroll
      for (int i = 0; i < 4; i++)
        z[(size_t)(rbase + i) * D + c] = acc[mi][ni][i] + bo[c];
    }
  }
}

// ---------------- flash attention: swapped-QK^T 32x32 structure ----------------
// (unchanged from round 6: 117 us, MfmaUtil 25%)
__global__ __launch_bounds__(256) void k_attn(const ushort_t* __restrict__ q_ws,
                                              const ushort_t* __restrict__ k_ws,
                                              const ushort_t* __restrict__ vT_ws,
                                              ushort_t* __restrict__ attn_bf) {
  __shared__ __align__(16) char lds[2][16384];   // [buf][K 8KB | Vt 8KB]
  const int bid = blockIdx.x;
  const int bh = ((bid & 7) << 3) | (bid >> 7);
  const int qt = (bid >> 3) & 15;
  const int bb = bh >> 4, hh = bh & 15;
  const char* qp = (const char*)(q_ws + (size_t)bh * S * 64);
  const char* kp = (const char*)(k_ws + (size_t)bh * S * 64);
  const char* vp = (const char*)(vT_ws + (size_t)bh * 64 * S);

  const int t = threadIdx.x, lane = t & 63, w = t >> 6;
  const int l31 = lane & 31, hi = lane >> 5;
  const int swz = (lane & 7) << 4;

  const int o0 = t * 16;
  const int r0 = o0 >> 7, c0 = (o0 & 127) ^ ((r0 & 7) << 4);
  const int o1 = 4096 + t * 16;
  const int r1 = o1 >> 7, c1 = (o1 & 127) ^ ((r1 & 7) << 4);

  const char* qrow = qp + (size_t)(qt * 128 + w * 32 + l31) * 128;
  bf16x8 qf[4];
#pragma unroll
  for (int w16 = 0; w16 < 4; ++w16)
    qf[w16] = *(const bf16x8*)(qrow + w16 * 32 + hi * 16);

  f32x16 oA, oB;
#pragma unroll
  for (int r = 0; r < 16; ++r) { oA[r] = 0.f; oB[r] = 0.f; }
  float m_run = -1e30f, l_run = 0.f;

  gload_lds16(kp + r0 * 128 + c0,  lds[0] + w * 1024);
  gload_lds16(kp + r1 * 128 + c1,  lds[0] + 4096 + w * 1024);
  gload_lds16(vp + r0 * 4096 + c0, lds[0] + 8192 + w * 1024);
  gload_lds16(vp + r1 * 4096 + c1, lds[0] + 12288 + w * 1024);
  __syncthreads();

  for (int tt = 0; tt < 32; ++tt) {
    const int cur = tt & 1;
    const char* Klds = lds[cur];
    const char* Vlds = lds[cur] + 8192;
    if (tt + 1 < 32) {
      char* dN = lds[cur ^ 1];
      const int nb = tt + 1;
      gload_lds16(kp + nb * 8192 + r0 * 128 + c0, dN + w * 1024);
      gload_lds16(kp + nb * 8192 + r1 * 128 + c1, dN + 4096 + w * 1024);
      gload_lds16(vp + r0 * 4096 + nb * 128 + c0, dN + 8192 + w * 1024);
      gload_lds16(vp + r1 * 4096 + nb * 128 + c1, dN + 12288 + w * 1024);
    }

    f32x16 sA, sB;
#pragma unroll
    for (int r = 0; r < 16; ++r) { sA[r] = 0.f; sB[r] = 0.f; }
    const char* kb = Klds + l31 * 128;
    __builtin_amdgcn_s_setprio(1);
#pragma unroll
    for (int w16 = 0; w16 < 4; ++w16) {
      const int col = w16 * 32 + hi * 16;
      bf16x8 k0 = *(const bf16x8*)(kb + (col ^ swz));
      bf16x8 k1 = *(const bf16x8*)(kb + 4096 + (col ^ swz));
      sA = __builtin_amdgcn_mfma_f32_32x32x16_bf16(k0, qf[w16], sA, 0, 0, 0);
      sB = __builtin_amdgcn_mfma_f32_32x32x16_bf16(k1, qf[w16], sB, 0, 0, 0);
    }
    __builtin_amdgcn_s_setprio(0);

    float mx = sA[0];
#pragma unroll
    for (int r = 1; r < 16; ++r) mx = fmaxf(mx, sA[r]);
#pragma unroll
    for (int r = 0; r < 16; ++r) mx = fmaxf(mx, sB[r]);
    mx = fmaxf(mx, __shfl_xor(mx, 32, 64));
    if (__any(mx > m_run + 11.5416f)) {
      float nm = fmaxf(m_run, mx);
      float corr = __builtin_amdgcn_exp2f(m_run - nm);
      l_run *= corr;
#pragma unroll
      for (int r = 0; r < 16; ++r) { oA[r] *= corr; oB[r] *= corr; }
      m_run = nm;
    }
    float rs = 0.f;
#pragma unroll
    for (int r = 0; r < 16; ++r) {
      sA[r] = __builtin_amdgcn_exp2f(sA[r] - m_run);
      sB[r] = __builtin_amdgcn_exp2f(sB[r] - m_run);
      rs += sA[r] + sB[r];
    }
    rs += __shfl_xor(rs, 32, 64);
    l_run += rs;

    unsigned pk0[8], pk1[8];
#pragma unroll
    for (int g = 0; g < 4; ++g) {
      pk0[2*g]   = cvtpk(sA[4*g],   sA[4*g+1]);
      pk0[2*g+1] = cvtpk(sA[4*g+2], sA[4*g+3]);
      pk1[2*g]   = cvtpk(sB[4*g],   sB[4*g+1]);
      pk1[2*g+1] = cvtpk(sB[4*g+2], sB[4*g+3]);
    }
    xch4(pk0[0], pk0[1], pk0[2], pk0[3], hi);
    xch4(pk0[4], pk0[5], pk0[6], pk0[7], hi);
    xch4(pk1[0], pk1[1], pk1[2], pk1[3], hi);
    xch4(pk1[4], pk1[5], pk1[6], pk1[7], hi);
    bf16x8 pf[4];
    pf[0] = __builtin_bit_cast(bf16x8, u32x4{pk0[0], pk0[1], pk0[2], pk0[3]});
    pf[1] = __builtin_bit_cast(bf16x8, u32x4{pk0[4], pk0[5], pk0[6], pk0[7]});
    pf[2] = __builtin_bit_cast(bf16x8, u32x4{pk1[0], pk1[1], pk1[2], pk1[3]});
    pf[3] = __builtin_bit_cast(bf16x8, u32x4{pk1[4], pk1[5], pk1[6], pk1[7]});

    const char* vb = Vlds + l31 * 128;
    __builtin_amdgcn_s_setprio(1);
#pragma unroll
    for (int ks = 0; ks < 4; ++ks) {
      const int colv = ks * 32 + hi * 16;
      bf16x8 v0 = *(const bf16x8*)(vb + (colv ^ swz));
      bf16x8 v1 = *(const bf16x8*)(vb + 4096 + (colv ^ swz));
      oA = __builtin_amdgcn_mfma_f32_32x32x16_bf16(v0, pf[ks], oA, 0, 0, 0);
      oB = __builtin_amdgcn_mfma_f32_32x32x16_bf16(v1, pf[ks], oB, 0, 0, 0);
    }
    __builtin_amdgcn_s_setprio(0);

    __syncthreads();
  }

  const float inv = 1.f / l_run;
  unsigned ok0[8], ok1[8];
#pragma unroll
  for (int g = 0; g < 4; ++g) {
    ok0[2*g]   = cvtpk(oA[4*g] * inv,   oA[4*g+1] * inv);
    ok0[2*g+1] = cvtpk(oA[4*g+2] * inv, oA[4*g+3] * inv);
    ok1[2*g]   = cvtpk(oB[4*g] * inv,   oB[4*g+1] * inv);
    ok1[2*g+1] = cvtpk(oB[4*g+2] * inv, oB[4*g+3] * inv);
  }
  xch4(ok0[0], ok0[1], ok0[2], ok0[3], hi);
  xch4(ok0[4], ok0[5], ok0[6], ok0[7], hi);
  xch4(ok1[0], ok1[1], ok1[2], ok1[3], hi);
  xch4(ok1[4], ok1[5], ok1[6], ok1[7], hi);

  const int grow = bb * S + qt * 128 + w * 32 + l31;
  ushort_t* orow = attn_bf + (size_t)grow * 1024 + hh * 64;
  *(u32x4*)(orow + 8 * hi)      = u32x4{ok0[0], ok0[1], ok0[2], ok0[3]};
  *(u32x4*)(orow + 16 + 8 * hi) = u32x4{ok0[4], ok0[5], ok0[6], ok0[7]};
  *(u32x4*)(orow + 32 + 8 * hi) = u32x4{ok1[0], ok1[1], ok1[2], ok1[3]};
  *(u32x4*)(orow + 48 + 8 * hi) = u32x4{ok1[4], ok1[5], ok1[6], ok1[7]};
}

// ---------------- residual + layernorm ----------------
__global__ __launch_bounds__(256) void k_ln(const float* __restrict__ z,
                                            const float* __restrict__ x,
                                            const float* __restrict__ lnw,
                                            const float* __restrict__ lnb,
                                            float* __restrict__ out) {
  const int r = blockIdx.x;
  const int t = threadIdx.x, lane = t & 63, w = t >> 6;
  float4 zv = ((const float4*)(z + r * D))[t];
  float4 xv = ((const float4*)(x + r * D))[t];
  float y[4] = {zv.x + xv.x, zv.y + xv.y, zv.z + xv.z, zv.w + xv.w};
  float sum = y[0] + y[1] + y[2] + y[3];
  float sq  = y[0]*y[0] + y[1]*y[1] + y[2]*y[2] + y[3]*y[3];
#pragma unroll
  for (int d = 1; d < 64; d <<= 1) { sum += __shfl_xor(sum, d, 64); sq += __shfl_xor(sq, d, 64); }
  __shared__ float ssum[4], ssq[4];
  if (lane == 0) { ssum[w] = sum; ssq[w] = sq; }
  __syncthreads();
  sum = ssum[0] + ssum[1] + ssum[2] + ssum[3];
  sq  = ssq[0] + ssq[1] + ssq[2] + ssq[3];
  float mean = sum * (1.f / D);
  float var  = sq * (1.f / D) - mean * mean;
  float rstd = rsqrtf(var + 1e-5f);
  float4 wv = ((const float4*)lnw)[t];
  float4 bv = ((const float4*)lnb)[t];
  float4 ov;
  ov.x = (y[0] - mean) * rstd * wv.x + bv.x;
  ov.y = (y[1] - mean) * rstd * wv.y + bv.y;
  ov.z = (y[2] - mean) * rstd * wv.z + bv.z;
  ov.w = (y[3] - mean) * rstd * wv.w + bv.w;
  ((float4*)(out + r * D))[t] = ov;
}

// ---------------- launcher ----------------
extern "C" void kernel_launch(void* const* d_in, const int* in_sizes, int n_in,
                              void* d_out, int out_size, void* d_ws, size_t ws_size,
                              hipStream_t stream) {
  const float* x   = (const float*)d_in[0];
  const float* Wq  = (const float*)d_in[1];
  const float* bq  = (const float*)d_in[2];
  const float* Wk  = (const float*)d_in[3];
  const float* bk  = (const float*)d_in[4];
  const float* Wv  = (const float*)d_in[5];
  const float* bv  = (const float*)d_in[6];
  const float* Wo  = (const float*)d_in[7];
  const float* bo  = (const float*)d_in[8];
  const float* lnw = (const float*)d_in[9];
  const float* lnb = (const float*)d_in[10];

  char* ws = (char*)d_ws;
  ushort_t* xb    = (ushort_t*)(ws + 0);           // 16,777,216
  ushort_t* q_ws  = (ushort_t*)(ws + 16777216);    // 16,777,216
  ushort_t* wt    = (ushort_t*)(ws + 33554432);    //  6,291,456
  ushort_t* wot   = (ushort_t*)(ws + 39845888);    //  2,097,152
  ushort_t* k_ws  = (ushort_t*)(ws + 41943040);    // 16,777,216
  ushort_t* vT_ws = (ushort_t*)(ws + 58720256);    // 16,777,216
  ushort_t* attn  = (ushort_t*)(ws + 75497472);    // 16,777,216  (total 92,274,688)
  float*    z     = (float*)(ws + 0);              // 33,554,432 alias over xb+q_ws

  k_conv_x<<<8192, 256, 0, stream>>>(x, xb);
  k_conv_w<<<12288, 256, 0, stream>>>(Wq, Wk, Wv, wt);
  k_conv_wo<<<4096, 256, 0, stream>>>(Wo, wot);
  k_qkv_gemm<<<384, 512, 0, stream>>>(xb, wt, bq, bk, bv, q_ws, k_ws, vT_ws);
  k_attn<<<B * H * (S / 128), 256, 0, stream>>>(q_ws, k_ws, vT_ws, attn);
  k_out_gemm<<<128, 512, 0, stream>>>(attn, wot, bo, z);
  k_ln<<<BS, 256, 0, stream>>>(z, x, lnw, lnb, (float*)d_out);
}

// Round 8
// 316.264 us; speedup vs baseline: 1.1918x; 1.1918x over previous
//
#include <hip/hip_runtime.h>
#include <hip/hip_bf16.h>
#include <stdint.h>

// ---- problem constants ----
constexpr int D  = 1024;
constexpr int H  = 16;
constexpr int DH = 64;
constexpr int B  = 4;
constexpr int S  = 2048;
constexpr int BS = B * S;          // 8192
constexpr int NQKV = 3 * D;        // 3072

typedef __attribute__((ext_vector_type(8))) short bf16x8;
typedef __attribute__((ext_vector_type(4))) float f32x4;
typedef __attribute__((ext_vector_type(16))) float f32x16;
typedef __attribute__((ext_vector_type(4))) unsigned short us4;
typedef __attribute__((ext_vector_type(4))) unsigned int u32x4;
typedef unsigned short ushort_t;

using gu32 = __attribute__((address_space(1))) unsigned int;
using lu32 = __attribute__((address_space(3))) unsigned int;

__device__ __forceinline__ void gload_lds16(const void* g, void* l) {
  __builtin_amdgcn_global_load_lds((gu32*)g, (lu32*)l, 16, 0, 0);
}

__device__ __forceinline__ ushort_t f2bf(float f) {
  uint32_t u = __builtin_bit_cast(uint32_t, f);
  u += 0x7FFFu + ((u >> 16) & 1u);
  return (ushort_t)(u >> 16);
}

// packed f32x2 -> bf16x2 (src0 -> low 16, src1 -> high 16)
__device__ __forceinline__ unsigned cvtpk(float lo, float hi) {
  unsigned r;
  asm("v_cvt_pk_bf16_f32 %0, %1, %2" : "=v"(r) : "v"(lo), "v"(hi));
  return r;
}

// Cross-half exchange: lo-lane keeps w0,w1, gets other half's w0,w1 into w2,w3;
// hi-lane keeps w2,w3 (in place), gets other half's w2,w3 into w0,w1.
__device__ __forceinline__ void xch4(unsigned& w0, unsigned& w1,
                                     unsigned& w2, unsigned& w3, int hi) {
  unsigned sx = hi ? w0 : w2;               // what this lane sends
  unsigned sy = hi ? w1 : w3;
  sx = (unsigned)__shfl_xor((int)sx, 32, 64);
  sy = (unsigned)__shfl_xor((int)sy, 32, 64);
  if (hi) { w0 = sx; w1 = sy; } else { w2 = sx; w3 = sy; }
}

// ---------------- conversion kernels ----------------
__global__ __launch_bounds__(256) void k_conv_x(const float* __restrict__ x,
                                                ushort_t* __restrict__ xb) {
  int i = (blockIdx.x * 256 + threadIdx.x) * 4;
  float4 v = *(const float4*)(x + i);
  us4 o;
  o[0] = f2bf(v.x); o[1] = f2bf(v.y); o[2] = f2bf(v.z); o[3] = f2bf(v.w);
  *(us4*)(xb + i) = o;
}

// Wcat_t [3072][1024]: coalesced LDS 64x64 transpose.
// grid 768 = which(3) x h(16) x dblk(16). wt[(which*1024+h*64+e)][d] = W[h][d][e]
__global__ __launch_bounds__(256) void k_conv_w(const float* __restrict__ Wq,
                                                const float* __restrict__ Wk,
                                                const float* __restrict__ Wv,
                                                ushort_t* __restrict__ wt) {
  __shared__ ushort_t tile[64][65];
  const int bid = blockIdx.x;
  const int which = bid >> 8;
  const int hh = (bid >> 4) & 15;
  const int d0 = (bid & 15) * 64;
  const float* src = (which == 0) ? Wq : (which == 1) ? Wk : Wv;
  const int t = threadIdx.x;
  const int dd = t >> 4, e4 = (t & 15) * 4;
#pragma unroll
  for (int p = 0; p < 4; ++p) {
    int d = dd + p * 16;
    float4 v = *(const float4*)(src + ((size_t)hh * D + d0 + d) * DH + e4);
    tile[e4 + 0][d] = f2bf(v.x);
    tile[e4 + 1][d] = f2bf(v.y);
    tile[e4 + 2][d] = f2bf(v.z);
    tile[e4 + 3][d] = f2bf(v.w);
  }
  __syncthreads();
  const int e = t >> 2, dp = (t & 3) * 16;
  ushort_t* dst = wt + (size_t)(which * 1024 + hh * 64 + e) * 1024 + d0 + dp;
  us4 o[4];
#pragma unroll
  for (int g = 0; g < 4; ++g)
#pragma unroll
    for (int j = 0; j < 4; ++j) o[g][j] = tile[e][dp + g * 4 + j];
#pragma unroll
  for (int g = 0; g < 4; ++g) *(us4*)(dst + g * 4) = o[g];
}

// Wo_t [1024][1024]: coalesced LDS 64x64 transpose. grid 256 = cblk(16) x dblk(16)
__global__ __launch_bounds__(256) void k_conv_wo(const float* __restrict__ Wo,
                                                 ushort_t* __restrict__ wot) {
  __shared__ ushort_t tile[64][65];
  const int bid = blockIdx.x;
  const int c0 = (bid >> 4) * 64;
  const int d0 = (bid & 15) * 64;
  const int t = threadIdx.x;
  const int dd = t >> 4, e4 = (t & 15) * 4;
#pragma unroll
  for (int p = 0; p < 4; ++p) {
    int d = dd + p * 16;
    float4 v = *(const float4*)(Wo + (size_t)(d0 + d) * 1024 + c0 + e4);
    tile[e4 + 0][d] = f2bf(v.x);
    tile[e4 + 1][d] = f2bf(v.y);
    tile[e4 + 2][d] = f2bf(v.z);
    tile[e4 + 3][d] = f2bf(v.w);
  }
  __syncthreads();
  const int e = t >> 2, dp = (t & 3) * 16;
  ushort_t* dst = wot + (size_t)(c0 + e) * 1024 + d0 + dp;
  us4 o[4];
#pragma unroll
  for (int g = 0; g < 4; ++g)
#pragma unroll
    for (int j = 0; j < 4; ++j) o[g][j] = tile[e][dp + g * 4 + j];
#pragma unroll
  for (int g = 0; g < 4; ++g) *(us4*)(dst + g * 4) = o[g];
}

// ---- GEMM core: BM=256 x BN=128, BK=32, 8 waves (4M x 2N), 3-buffer counted vmcnt ----
// K fixed = 1024 (32 tiles). A [M][1024], Bt [N][1024] bf16 row-major (2048B rows).
// Buffer (24KB): A rows 0-127 [0,8K), rows 128-255 [8K,16K), B rows 0-127 [16K,24K).
// Swizzle chunk ^= (row>>1)&3 both-sides -> 8 lanes per 16B bank-quad = conflict-free.
__device__ __forceinline__ void gemm_core_256x128(const ushort_t* __restrict__ A,
                                                  const ushort_t* __restrict__ Bt,
                                                  int m0, int n0,
                                                  f32x4 acc[4][4], char* lds) {
  const int t = threadIdx.x;
  const int lane = t & 63, w = t >> 6;
  const int wm = w >> 1, wn = w & 1;            // wm 0..3 (64 rows), wn 0..1 (64 cols)
  const int lrow = lane & 15;
  const int chx = (((lane >> 4) ^ ((lrow >> 1) & 3)) << 4);

#pragma unroll
  for (int mi = 0; mi < 4; mi++)
#pragma unroll
    for (int ni = 0; ni < 4; ni++) acc[mi][ni] = f32x4{0.f, 0.f, 0.f, 0.f};

  const int prow = t >> 2;                      // 0..127
  const int sw16 = (((t & 3) ^ ((prow >> 1) & 3)) << 4);
  const char* sA0 = (const char*)A  + (size_t)(m0 + prow) * 2048 + sw16;
  const char* sB0 = (const char*)Bt + (size_t)(n0 + prow) * 2048 + sw16;

  auto STAGE = [&](int kt) {
    char* bb = lds + (kt % 3) * 24576;
    const size_t ko = (size_t)kt * 64;
    gload_lds16(sA0 + ko,              bb + w * 1024);
    gload_lds16(sA0 + 128 * 2048 + ko, bb + 8192 + w * 1024);
    gload_lds16(sB0 + ko,              bb + 16384 + w * 1024);
  };

  STAGE(0); STAGE(1);                           // 6 VMEM ops in flight

  for (int kt = 0; kt < 32; ++kt) {
    if (kt < 31) asm volatile("s_waitcnt vmcnt(3)" ::: "memory");
    else         asm volatile("s_waitcnt vmcnt(0)" ::: "memory");
    __builtin_amdgcn_sched_barrier(0);
    __builtin_amdgcn_s_barrier();               // raw barrier: no vmcnt(0) drain
    __builtin_amdgcn_sched_barrier(0);
    if (kt + 2 < 32) STAGE(kt + 2);             // overwrites buf (kt-1)%3: all waves
                                                // consumed it before this barrier
    const char* bb = lds + (kt % 3) * 24576;
    const char* aB = bb + wm * 4096 + lrow * 64 + chx;
    const char* bB = bb + 16384 + wn * 4096 + lrow * 64 + chx;
    bf16x8 af[4], bf[4];
#pragma unroll
    for (int mi = 0; mi < 4; mi++) af[mi] = *(const bf16x8*)(aB + mi * 1024);
#pragma unroll
    for (int ni = 0; ni < 4; ni++) bf[ni] = *(const bf16x8*)(bB + ni * 1024);
    __builtin_amdgcn_s_setprio(1);
#pragma unroll
    for (int mi = 0; mi < 4; mi++)
#pragma unroll
      for (int ni = 0; ni < 4; ni++)
        acc[mi][ni] = __builtin_amdgcn_mfma_f32_16x16x32_bf16(af[mi], bf[ni], acc[mi][ni], 0, 0, 0);
    __builtin_amdgcn_s_setprio(0);
  }
}

// QKV GEMM: grid 32x24 = 768 (3 clean rounds), XCD-swizzled; bias + scatter epilogue
__global__ __launch_bounds__(512, 2) void k_qkv_gemm(const ushort_t* __restrict__ xb,
                                                     const ushort_t* __restrict__ wt,
                                                     const float* __restrict__ bq,
                                                     const float* __restrict__ bk,
                                                     const float* __restrict__ bv,
                                                     ushort_t* __restrict__ q_ws,
                                                     ushort_t* __restrict__ k_ws,
                                                     ushort_t* __restrict__ vT_ws) {
  __shared__ __align__(16) char lds[3][24576];
  const int bid = blockIdx.x;
  const int wg = (bid & 7) * 96 + (bid >> 3);   // 768 % 8 == 0: bijective
  const int tm = wg / 24, tn = wg - tm * 24;
  const int m0 = tm * 256, n0 = tn * 128;
  f32x4 acc[4][4];
  gemm_core_256x128(xb, wt, m0, n0, acc, &lds[0][0]);

  constexpr float QSC = 0.18033688011112042f;   // 0.125 * log2(e)
  const int t = threadIdx.x, lane = t & 63, w = t >> 6;
  const int wm = w >> 1, wn = w & 1;
  const int lrow = lane & 15, lgrp = lane >> 4;
#pragma unroll
  for (int mi = 0; mi < 4; mi++) {
    int rbase = m0 + wm * 64 + mi * 16 + lgrp * 4;
    int bb = rbase >> 11, ss0 = rbase & 2047;
#pragma unroll
    for (int ni = 0; ni < 4; ni++) {
      int c = n0 + wn * 64 + ni * 16 + lrow;
      int which = c >> 10, cl = c & 1023;
      int hh = cl >> 6, e = cl & 63;
      if (which == 0) {
        float bias = bq[cl];
#pragma unroll
        for (int i = 0; i < 4; i++)
          q_ws[((bb * H + hh) * S + ss0 + i) * 64 + e] = f2bf((acc[mi][ni][i] + bias) * QSC);
      } else if (which == 1) {
        float bias = bk[cl];
#pragma unroll
        for (int i = 0; i < 4; i++)
          k_ws[((bb * H + hh) * S + ss0 + i) * 64 + e] = f2bf(acc[mi][ni][i] + bias);
      } else {
        float bias = bv[cl];
        us4 pv;
#pragma unroll
        for (int i = 0; i < 4; i++) pv[i] = f2bf(acc[mi][ni][i] + bias);
        *(us4*)(vT_ws + (size_t)((bb * H + hh) * 64 + e) * S + ss0) = pv;  // 8B packed
      }
    }
  }
}

// Output GEMM: grid 32x8 = 256 (exactly 1/CU); z fp32 + bias
__global__ __launch_bounds__(512, 2) void k_out_gemm(const ushort_t* __restrict__ attn_bf,
                                                     const ushort_t* __restrict__ wot,
                                                     const float* __restrict__ bo,
                                                     float* __restrict__ z) {
  __shared__ __align__(16) char lds[3][24576];
  const int bid = blockIdx.x;
  const int wg = (bid & 7) * 32 + (bid >> 3);   // 256 % 8 == 0: bijective
  const int tm = wg >> 3, tn = wg & 7;
  const int m0 = tm * 256, n0 = tn * 128;
  f32x4 acc[4][4];
  gemm_core_256x128(attn_bf, wot, m0, n0, acc, &lds[0][0]);

  const int t = threadIdx.x, lane = t & 63, w = t >> 6;
  const int wm = w >> 1, wn = w & 1;
  const int lrow = lane & 15, lgrp = lane >> 4;
#pragma unroll
  for (int mi = 0; mi < 4; mi++) {
    int rbase = m0 + wm * 64 + mi * 16 + lgrp * 4;
#pragma unroll
    for (int ni = 0; ni < 4; ni++) {
      int c = n0 + wn * 64 + ni * 16 + lrow;
#pragma unroll
      for (int i = 0; i < 4; i++)
        z[(size_t)(rbase + i) * D + c] = acc[mi][ni][i] + bo[c];
    }
  }
}

// ---------------- flash attention (unchanged: 117-119 us, verified twice) ----------------
__global__ __launch_bounds__(256) void k_attn(const ushort_t* __restrict__ q_ws,
                                              const ushort_t* __restrict__ k_ws,
                                              const ushort_t* __restrict__ vT_ws,
                                              ushort_t* __restrict__ attn_bf) {
  __shared__ __align__(16) char lds[2][16384];   // [buf][K 8KB | Vt 8KB]
  const int bid = blockIdx.x;
  const int bh = ((bid & 7) << 3) | (bid >> 7);
  const int qt = (bid >> 3) & 15;
  const int bb = bh >> 4, hh = bh & 15;
  const char* qp = (const char*)(q_ws + (size_t)bh * S * 64);
  const char* kp = (const char*)(k_ws + (size_t)bh * S * 64);
  const char* vp = (const char*)(vT_ws + (size_t)bh * 64 * S);

  const int t = threadIdx.x, lane = t & 63, w = t >> 6;
  const int l31 = lane & 31, hi = lane >> 5;
  const int swz = (lane & 7) << 4;

  const int o0 = t * 16;
  const int r0 = o0 >> 7, c0 = (o0 & 127) ^ ((r0 & 7) << 4);
  const int o1 = 4096 + t * 16;
  const int r1 = o1 >> 7, c1 = (o1 & 127) ^ ((r1 & 7) << 4);

  const char* qrow = qp + (size_t)(qt * 128 + w * 32 + l31) * 128;
  bf16x8 qf[4];
#pragma unroll
  for (int w16 = 0; w16 < 4; ++w16)
    qf[w16] = *(const bf16x8*)(qrow + w16 * 32 + hi * 16);

  f32x16 oA, oB;
#pragma unroll
  for (int r = 0; r < 16; ++r) { oA[r] = 0.f; oB[r] = 0.f; }
  float m_run = -1e30f, l_run = 0.f;

  gload_lds16(kp + r0 * 128 + c0,  lds[0] + w * 1024);
  gload_lds16(kp + r1 * 128 + c1,  lds[0] + 4096 + w * 1024);
  gload_lds16(vp + r0 * 4096 + c0, lds[0] + 8192 + w * 1024);
  gload_lds16(vp + r1 * 4096 + c1, lds[0] + 12288 + w * 1024);
  __syncthreads();

  for (int tt = 0; tt < 32; ++tt) {
    const int cur = tt & 1;
    const char* Klds = lds[cur];
    const char* Vlds = lds[cur] + 8192;
    if (tt + 1 < 32) {
      char* dN = lds[cur ^ 1];
      const int nb = tt + 1;
      gload_lds16(kp + nb * 8192 + r0 * 128 + c0, dN + w * 1024);
      gload_lds16(kp + nb * 8192 + r1 * 128 + c1, dN + 4096 + w * 1024);
      gload_lds16(vp + r0 * 4096 + nb * 128 + c0, dN + 8192 + w * 1024);
      gload_lds16(vp + r1 * 4096 + nb * 128 + c1, dN + 12288 + w * 1024);
    }

    f32x16 sA, sB;
#pragma unroll
    for (int r = 0; r < 16; ++r) { sA[r] = 0.f; sB[r] = 0.f; }
    const char* kb = Klds + l31 * 128;
    __builtin_amdgcn_s_setprio(1);
#pragma unroll
    for (int w16 = 0; w16 < 4; ++w16) {
      const int col = w16 * 32 + hi * 16;
      bf16x8 k0 = *(const bf16x8*)(kb + (col ^ swz));
      bf16x8 k1 = *(const bf16x8*)(kb + 4096 + (col ^ swz));
      sA = __builtin_amdgcn_mfma_f32_32x32x16_bf16(k0, qf[w16], sA, 0, 0, 0);
      sB = __builtin_amdgcn_mfma_f32_32x32x16_bf16(k1, qf[w16], sB, 0, 0, 0);
    }
    __builtin_amdgcn_s_setprio(0);

    float mx = sA[0];
#pragma unroll
    for (int r = 1; r < 16; ++r) mx = fmaxf(mx, sA[r]);
#pragma unroll
    for (int r = 0; r < 16; ++r) mx = fmaxf(mx, sB[r]);
    mx = fmaxf(mx, __shfl_xor(mx, 32, 64));
    if (__any(mx > m_run + 11.5416f)) {
      float nm = fmaxf(m_run, mx);
      float corr = __builtin_amdgcn_exp2f(m_run - nm);
      l_run *= corr;
#pragma unroll
      for (int r = 0; r < 16; ++r) { oA[r] *= corr; oB[r] *= corr; }
      m_run = nm;
    }
    float rs = 0.f;
#pragma unroll
    for (int r = 0; r < 16; ++r) {
      sA[r] = __builtin_amdgcn_exp2f(sA[r] - m_run);
      sB[r] = __builtin_amdgcn_exp2f(sB[r] - m_run);
      rs += sA[r] + sB[r];
    }
    rs += __shfl_xor(rs, 32, 64);
    l_run += rs;

    unsigned pk0[8], pk1[8];
#pragma unroll
    for (int g = 0; g < 4; ++g) {
      pk0[2*g]   = cvtpk(sA[4*g],   sA[4*g+1]);
      pk0[2*g+1] = cvtpk(sA[4*g+2], sA[4*g+3]);
      pk1[2*g]   = cvtpk(sB[4*g],   sB[4*g+1]);
      pk1[2*g+1] = cvtpk(sB[4*g+2], sB[4*g+3]);
    }
    xch4(pk0[0], pk0[1], pk0[2], pk0[3], hi);
    xch4(pk0[4], pk0[5], pk0[6], pk0[7], hi);
    xch4(pk1[0], pk1[1], pk1[2], pk1[3], hi);
    xch4(pk1[4], pk1[5], pk1[6], pk1[7], hi);
    bf16x8 pf[4];
    pf[0] = __builtin_bit_cast(bf16x8, u32x4{pk0[0], pk0[1], pk0[2], pk0[3]});
    pf[1] = __builtin_bit_cast(bf16x8, u32x4{pk0[4], pk0[5], pk0[6], pk0[7]});
    pf[2] = __builtin_bit_cast(bf16x8, u32x4{pk1[0], pk1[1], pk1[2], pk1[3]});
    pf[3] = __builtin_bit_cast(bf16x8, u32x4{pk1[4], pk1[5], pk1[6], pk1[7]});

    const char* vb = Vlds + l31 * 128;
    __builtin_amdgcn_s_setprio(1);
#pragma unroll
    for (int ks = 0; ks < 4; ++ks) {
      const int colv = ks * 32 + hi * 16;
      bf16x8 v0 = *(const bf16x8*)(vb + (colv ^ swz));
      bf16x8 v1 = *(const bf16x8*)(vb + 4096 + (colv ^ swz));
      oA = __builtin_amdgcn_mfma_f32_32x32x16_bf16(v0, pf[ks], oA, 0, 0, 0);
      oB = __builtin_amdgcn_mfma_f32_32x32x16_bf16(v1, pf[ks], oB, 0, 0, 0);
    }
    __builtin_amdgcn_s_setprio(0);

    __syncthreads();
  }

  const float inv = 1.f / l_run;
  unsigned ok0[8], ok1[8];
#pragma unroll
  for (int g = 0; g < 4; ++g) {
    ok0[2*g]   = cvtpk(oA[4*g] * inv,   oA[4*g+1] * inv);
    ok0[2*g+1] = cvtpk(oA[4*g+2] * inv, oA[4*g+3] * inv);
    ok1[2*g]   = cvtpk(oB[4*g] * inv,   oB[4*g+1] * inv);
    ok1[2*g+1] = cvtpk(oB[4*g+2] * inv, oB[4*g+3] * inv);
  }
  xch4(ok0[0], ok0[1], ok0[2], ok0[3], hi);
  xch4(ok0[4], ok0[5], ok0[6], ok0[7], hi);
  xch4(ok1[0], ok1[1], ok1[2], ok1[3], hi);
  xch4(ok1[4], ok1[5], ok1[6], ok1[7], hi);

  const int grow = bb * S + qt * 128 + w * 32 + l31;
  ushort_t* orow = attn_bf + (size_t)grow * 1024 + hh * 64;
  *(u32x4*)(orow + 8 * hi)      = u32x4{ok0[0], ok0[1], ok0[2], ok0[3]};
  *(u32x4*)(orow + 16 + 8 * hi) = u32x4{ok0[4], ok0[5], ok0[6], ok0[7]};
  *(u32x4*)(orow + 32 + 8 * hi) = u32x4{ok1[0], ok1[1], ok1[2], ok1[3]};
  *(u32x4*)(orow + 48 + 8 * hi) = u32x4{ok1[4], ok1[5], ok1[6], ok1[7]};
}

// ---------------- residual + layernorm ----------------
__global__ __launch_bounds__(256) void k_ln(const float* __restrict__ z,
                                            const float* __restrict__ x,
                                            const float* __restrict__ lnw,
                                            const float* __restrict__ lnb,
                                            float* __restrict__ out) {
  const int r = blockIdx.x;
  const int t = threadIdx.x, lane = t & 63, w = t >> 6;
  float4 zv = ((const float4*)(z + r * D))[t];
  float4 xv = ((const float4*)(x + r * D))[t];
  float y[4] = {zv.x + xv.x, zv.y + xv.y, zv.z + xv.z, zv.w + xv.w};
  float sum = y[0] + y[1] + y[2] + y[3];
  float sq  = y[0]*y[0] + y[1]*y[1] + y[2]*y[2] + y[3]*y[3];
#pragma unroll
  for (int d = 1; d < 64; d <<= 1) { sum += __shfl_xor(sum, d, 64); sq += __shfl_xor(sq, d, 64); }
  __shared__ float ssum[4], ssq[4];
  if (lane == 0) { ssum[w] = sum; ssq[w] = sq; }
  __syncthreads();
  sum = ssum[0] + ssum[1] + ssum[2] + ssum[3];
  sq  = ssq[0] + ssq[1] + ssq[2] + ssq[3];
  float mean = sum * (1.f / D);
  float var  = sq * (1.f / D) - mean * mean;
  float rstd = rsqrtf(var + 1e-5f);
  float4 wv = ((const float4*)lnw)[t];
  float4 bv = ((const float4*)lnb)[t];
  float4 ov;
  ov.x = (y[0] - mean) * rstd * wv.x + bv.x;
  ov.y = (y[1] - mean) * rstd * wv.y + bv.y;
  ov.z = (y[2] - mean) * rstd * wv.z + bv.z;
  ov.w = (y[3] - mean) * rstd * wv.w + bv.w;
  ((float4*)(out + r * D))[t] = ov;
}

// ---------------- launcher ----------------
extern "C" void kernel_launch(void* const* d_in, const int* in_sizes, int n_in,
                              void* d_out, int out_size, void* d_ws, size_t ws_size,
                              hipStream_t stream) {
  const float* x   = (const float*)d_in[0];
  const float* Wq  = (const float*)d_in[1];
  const float* bq  = (const float*)d_in[2];
  const float* Wk  = (const float*)d_in[3];
  const float* bk  = (const float*)d_in[4];
  const float* Wv  = (const float*)d_in[5];
  const float* bv  = (const float*)d_in[6];
  const float* Wo  = (const float*)d_in[7];
  const float* bo  = (const float*)d_in[8];
  const float* lnw = (const float*)d_in[9];
  const float* lnb = (const float*)d_in[10];

  char* ws = (char*)d_ws;
  ushort_t* xb    = (ushort_t*)(ws + 0);           // 16,777,216
  ushort_t* q_ws  = (ushort_t*)(ws + 16777216);    // 16,777,216
  ushort_t* wt    = (ushort_t*)(ws + 33554432);    //  6,291,456
  ushort_t* wot   = (ushort_t*)(ws + 39845888);    //  2,097,152
  ushort_t* k_ws  = (ushort_t*)(ws + 41943040);    // 16,777,216
  ushort_t* vT_ws = (ushort_t*)(ws + 58720256);    // 16,777,216
  ushort_t* attn  = (ushort_t*)(ws + 75497472);    // 16,777,216  (total 92,274,688)
  float*    z     = (float*)(ws + 0);              // 33,554,432 alias over xb+q_ws

  k_conv_x<<<8192, 256, 0, stream>>>(x, xb);
  k_conv_w<<<768, 256, 0, stream>>>(Wq, Wk, Wv, wt);
  k_conv_wo<<<256, 256, 0, stream>>>(Wo, wot);
  k_qkv_gemm<<<768, 512, 0, stream>>>(xb, wt, bq, bk, bv, q_ws, k_ws, vT_ws);
  k_attn<<<B * H * (S / 128), 256, 0, stream>>>(q_ws, k_ws, vT_ws, attn);
  k_out_gemm<<<256, 512, 0, stream>>>(attn, wot, bo, z);
  k_ln<<<BS, 256, 0, stream>>>(z, x, lnw, lnb, (float*)d_out);
}

// Round 9
// 293.658 us; speedup vs baseline: 1.2835x; 1.0770x over previous
//
#include <hip/hip_runtime.h>
#include <hip/hip_bf16.h>
#include <stdint.h>

// ---- problem constants ----
constexpr int D  = 1024;
constexpr int H  = 16;
constexpr int DH = 64;
constexpr int B  = 4;
constexpr int S  = 2048;
constexpr int BS = B * S;          // 8192
constexpr int NQKV = 3 * D;        // 3072

typedef __attribute__((ext_vector_type(8))) short bf16x8;
typedef __attribute__((ext_vector_type(4))) float f32x4;
typedef __attribute__((ext_vector_type(16))) float f32x16;
typedef __attribute__((ext_vector_type(4))) unsigned short us4;
typedef __attribute__((ext_vector_type(4))) unsigned int u32x4;
typedef unsigned short ushort_t;

using gu32 = __attribute__((address_space(1))) unsigned int;
using lu32 = __attribute__((address_space(3))) unsigned int;

__device__ __forceinline__ void gload_lds16(const void* g, void* l) {
  __builtin_amdgcn_global_load_lds((gu32*)g, (lu32*)l, 16, 0, 0);
}

__device__ __forceinline__ ushort_t f2bf(float f) {
  uint32_t u = __builtin_bit_cast(uint32_t, f);
  u += 0x7FFFu + ((u >> 16) & 1u);
  return (ushort_t)(u >> 16);
}

// packed f32x2 -> bf16x2 (src0 -> low 16, src1 -> high 16)
__device__ __forceinline__ unsigned cvtpk(float lo, float hi) {
  unsigned r;
  asm("v_cvt_pk_bf16_f32 %0, %1, %2" : "=v"(r) : "v"(lo), "v"(hi));
  return r;
}

// Cross-half exchange: lo-lane keeps w0,w1, gets other half's w0,w1 into w2,w3;
// hi-lane keeps w2,w3 (in place), gets other half's w2,w3 into w0,w1.
__device__ __forceinline__ void xch4(unsigned& w0, unsigned& w1,
                                     unsigned& w2, unsigned& w3, int hi) {
  unsigned sx = hi ? w0 : w2;               // what this lane sends
  unsigned sy = hi ? w1 : w3;
  sx = (unsigned)__shfl_xor((int)sx, 32, 64);
  sy = (unsigned)__shfl_xor((int)sy, 32, 64);
  if (hi) { w0 = sx; w1 = sy; } else { w2 = sx; w3 = sy; }
}

// ---------------- conversion kernels ----------------
__global__ __launch_bounds__(256) void k_conv_x(const float* __restrict__ x,
                                                ushort_t* __restrict__ xb) {
  int i = (blockIdx.x * 256 + threadIdx.x) * 4;
  float4 v = *(const float4*)(x + i);
  us4 o;
  o[0] = f2bf(v.x); o[1] = f2bf(v.y); o[2] = f2bf(v.z); o[3] = f2bf(v.w);
  *(us4*)(xb + i) = o;
}

// Wcat_t [3072][1024]: coalesced LDS 64x64 transpose.
// grid 768 = which(3) x h(16) x dblk(16). wt[(which*1024+h*64+e)][d] = W[h][d][e]
__global__ __launch_bounds__(256) void k_conv_w(const float* __restrict__ Wq,
                                                const float* __restrict__ Wk,
                                                const float* __restrict__ Wv,
                                                ushort_t* __restrict__ wt) {
  __shared__ ushort_t tile[64][65];
  const int bid = blockIdx.x;
  const int which = bid >> 8;
  const int hh = (bid >> 4) & 15;
  const int d0 = (bid & 15) * 64;
  const float* src = (which == 0) ? Wq : (which == 1) ? Wk : Wv;
  const int t = threadIdx.x;
  const int dd = t >> 4, e4 = (t & 15) * 4;
#pragma unroll
  for (int p = 0; p < 4; ++p) {
    int d = dd + p * 16;
    float4 v = *(const float4*)(src + ((size_t)hh * D + d0 + d) * DH + e4);
    tile[e4 + 0][d] = f2bf(v.x);
    tile[e4 + 1][d] = f2bf(v.y);
    tile[e4 + 2][d] = f2bf(v.z);
    tile[e4 + 3][d] = f2bf(v.w);
  }
  __syncthreads();
  const int e = t >> 2, dp = (t & 3) * 16;
  ushort_t* dst = wt + (size_t)(which * 1024 + hh * 64 + e) * 1024 + d0 + dp;
  us4 o[4];
#pragma unroll
  for (int g = 0; g < 4; ++g)
#pragma unroll
    for (int j = 0; j < 4; ++j) o[g][j] = tile[e][dp + g * 4 + j];
#pragma unroll
  for (int g = 0; g < 4; ++g) *(us4*)(dst + g * 4) = o[g];
}

// Wo_t [1024][1024]: coalesced LDS 64x64 transpose. grid 256 = cblk(16) x dblk(16)
__global__ __launch_bounds__(256) void k_conv_wo(const float* __restrict__ Wo,
                                                 ushort_t* __restrict__ wot) {
  __shared__ ushort_t tile[64][65];
  const int bid = blockIdx.x;
  const int c0 = (bid >> 4) * 64;
  const int d0 = (bid & 15) * 64;
  const int t = threadIdx.x;
  const int dd = t >> 4, e4 = (t & 15) * 4;
#pragma unroll
  for (int p = 0; p < 4; ++p) {
    int d = dd + p * 16;
    float4 v = *(const float4*)(Wo + (size_t)(d0 + d) * 1024 + c0 + e4);
    tile[e4 + 0][d] = f2bf(v.x);
    tile[e4 + 1][d] = f2bf(v.y);
    tile[e4 + 2][d] = f2bf(v.z);
    tile[e4 + 3][d] = f2bf(v.w);
  }
  __syncthreads();
  const int e = t >> 2, dp = (t & 3) * 16;
  ushort_t* dst = wot + (size_t)(c0 + e) * 1024 + d0 + dp;
  us4 o[4];
#pragma unroll
  for (int g = 0; g < 4; ++g)
#pragma unroll
    for (int j = 0; j < 4; ++j) o[g][j] = tile[e][dp + g * 4 + j];
#pragma unroll
  for (int g = 0; g < 4; ++g) *(us4*)(dst + g * 4) = o[g];
}

// ---- GEMM core: BM=256 x BN=128, BK=32, 8 waves (4M x 2N), 3-buffer counted vmcnt ----
__device__ __forceinline__ void gemm_core_256x128(const ushort_t* __restrict__ A,
                                                  const ushort_t* __restrict__ Bt,
                                                  int m0, int n0,
                                                  f32x4 acc[4][4], char* lds) {
  const int t = threadIdx.x;
  const int lane = t & 63, w = t >> 6;
  const int wm = w >> 1, wn = w & 1;            // wm 0..3 (64 rows), wn 0..1 (64 cols)
  const int lrow = lane & 15;
  const int chx = (((lane >> 4) ^ ((lrow >> 1) & 3)) << 4);

#pragma unroll
  for (int mi = 0; mi < 4; mi++)
#pragma unroll
    for (int ni = 0; ni < 4; ni++) acc[mi][ni] = f32x4{0.f, 0.f, 0.f, 0.f};

  const int prow = t >> 2;                      // 0..127
  const int sw16 = (((t & 3) ^ ((prow >> 1) & 3)) << 4);
  const char* sA0 = (const char*)A  + (size_t)(m0 + prow) * 2048 + sw16;
  const char* sB0 = (const char*)Bt + (size_t)(n0 + prow) * 2048 + sw16;

  auto STAGE = [&](int kt) {
    char* bb = lds + (kt % 3) * 24576;
    const size_t ko = (size_t)kt * 64;
    gload_lds16(sA0 + ko,              bb + w * 1024);
    gload_lds16(sA0 + 128 * 2048 + ko, bb + 8192 + w * 1024);
    gload_lds16(sB0 + ko,              bb + 16384 + w * 1024);
  };

  STAGE(0); STAGE(1);                           // 6 VMEM ops in flight

  for (int kt = 0; kt < 32; ++kt) {
    if (kt < 31) asm volatile("s_waitcnt vmcnt(3)" ::: "memory");
    else         asm volatile("s_waitcnt vmcnt(0)" ::: "memory");
    __builtin_amdgcn_sched_barrier(0);
    __builtin_amdgcn_s_barrier();               // raw barrier: no vmcnt(0) drain
    __builtin_amdgcn_sched_barrier(0);
    if (kt + 2 < 32) STAGE(kt + 2);
    const char* bb = lds + (kt % 3) * 24576;
    const char* aB = bb + wm * 4096 + lrow * 64 + chx;
    const char* bB = bb + 16384 + wn * 4096 + lrow * 64 + chx;
    bf16x8 af[4], bf[4];
#pragma unroll
    for (int mi = 0; mi < 4; mi++) af[mi] = *(const bf16x8*)(aB + mi * 1024);
#pragma unroll
    for (int ni = 0; ni < 4; ni++) bf[ni] = *(const bf16x8*)(bB + ni * 1024);
    __builtin_amdgcn_s_setprio(1);
#pragma unroll
    for (int mi = 0; mi < 4; mi++)
#pragma unroll
      for (int ni = 0; ni < 4; ni++)
        acc[mi][ni] = __builtin_amdgcn_mfma_f32_16x16x32_bf16(af[mi], bf[ni], acc[mi][ni], 0, 0, 0);
    __builtin_amdgcn_s_setprio(0);
  }
}

// QKV GEMM: grid 32x24 = 768 (3 clean rounds), XCD-swizzled; bias + scatter epilogue
__global__ __launch_bounds__(512, 2) void k_qkv_gemm(const ushort_t* __restrict__ xb,
                                                     const ushort_t* __restrict__ wt,
                                                     const float* __restrict__ bq,
                                                     const float* __restrict__ bk,
                                                     const float* __restrict__ bv,
                                                     ushort_t* __restrict__ q_ws,
                                                     ushort_t* __restrict__ k_ws,
                                                     ushort_t* __restrict__ vT_ws) {
  __shared__ __align__(16) char lds[3][24576];
  const int bid = blockIdx.x;
  const int wg = (bid & 7) * 96 + (bid >> 3);   // 768 % 8 == 0: bijective
  const int tm = wg / 24, tn = wg - tm * 24;
  const int m0 = tm * 256, n0 = tn * 128;
  f32x4 acc[4][4];
  gemm_core_256x128(xb, wt, m0, n0, acc, &lds[0][0]);

  constexpr float QSC = 0.18033688011112042f;   // 0.125 * log2(e)
  const int t = threadIdx.x, lane = t & 63, w = t >> 6;
  const int wm = w >> 1, wn = w & 1;
  const int lrow = lane & 15, lgrp = lane >> 4;
#pragma unroll
  for (int mi = 0; mi < 4; mi++) {
    int rbase = m0 + wm * 64 + mi * 16 + lgrp * 4;
    int bb = rbase >> 11, ss0 = rbase & 2047;
#pragma unroll
    for (int ni = 0; ni < 4; ni++) {
      int c = n0 + wn * 64 + ni * 16 + lrow;
      int which = c >> 10, cl = c & 1023;
      int hh = cl >> 6, e = cl & 63;
      if (which == 0) {
        float bias = bq[cl];
#pragma unroll
        for (int i = 0; i < 4; i++)
          q_ws[((bb * H + hh) * S + ss0 + i) * 64 + e] = f2bf((acc[mi][ni][i] + bias) * QSC);
      } else if (which == 1) {
        float bias = bk[cl];
#pragma unroll
        for (int i = 0; i < 4; i++)
          k_ws[((bb * H + hh) * S + ss0 + i) * 64 + e] = f2bf(acc[mi][ni][i] + bias);
      } else {
        float bias = bv[cl];
        us4 pv;
#pragma unroll
        for (int i = 0; i < 4; i++) pv[i] = f2bf(acc[mi][ni][i] + bias);
        *(us4*)(vT_ws + (size_t)((bb * H + hh) * 64 + e) * S + ss0) = pv;  // 8B packed
      }
    }
  }
}

// Output GEMM: grid 32x8 = 256 (exactly 1/CU); z fp32 + bias
__global__ __launch_bounds__(512, 2) void k_out_gemm(const ushort_t* __restrict__ attn_bf,
                                                     const ushort_t* __restrict__ wot,
                                                     const float* __restrict__ bo,
                                                     float* __restrict__ z) {
  __shared__ __align__(16) char lds[3][24576];
  const int bid = blockIdx.x;
  const int wg = (bid & 7) * 32 + (bid >> 3);   // 256 % 8 == 0: bijective
  const int tm = wg >> 3, tn = wg & 7;
  const int m0 = tm * 256, n0 = tn * 128;
  f32x4 acc[4][4];
  gemm_core_256x128(attn_bf, wot, m0, n0, acc, &lds[0][0]);

  const int t = threadIdx.x, lane = t & 63, w = t >> 6;
  const int wm = w >> 1, wn = w & 1;
  const int lrow = lane & 15, lgrp = lane >> 4;
#pragma unroll
  for (int mi = 0; mi < 4; mi++) {
    int rbase = m0 + wm * 64 + mi * 16 + lgrp * 4;
#pragma unroll
    for (int ni = 0; ni < 4; ni++) {
      int c = n0 + wn * 64 + ni * 16 + lrow;
#pragma unroll
      for (int i = 0; i < 4; i++)
        z[(size_t)(rbase + i) * D + c] = acc[mi][ni][i] + bo[c];
    }
  }
}

// ---------------- flash attention: QBLK=256, 8 waves, 512 blocks ----------------
// grid 512 = 64 bh x 8 q-tiles of 256 rows. Swapped-QK^T 32x32 structure per wave.
// 8 waves share one K/V LDS double-buffer -> staging bytes halved vs QBLK=128,
// and 2 waves/SIMD per block for better MFMA/VALU overlap.
__global__ __launch_bounds__(512, 4) void k_attn(const ushort_t* __restrict__ q_ws,
                                                 const ushort_t* __restrict__ k_ws,
                                                 const ushort_t* __restrict__ vT_ws,
                                                 ushort_t* __restrict__ attn_bf) {
  __shared__ __align__(16) char lds[2][16384];   // [buf][K 8KB | Vt 8KB]
  const int bid = blockIdx.x;                    // 512 blocks
  // XCD swizzle: all 8 q-tiles of one bh share bid&7 -> same XCD; bijective.
  const int bh = ((bid & 7) << 3) | (bid >> 6);
  const int qt = (bid >> 3) & 7;
  const int bb = bh >> 4, hh = bh & 15;
  const char* qp = (const char*)(q_ws + (size_t)bh * S * 64);
  const char* kp = (const char*)(k_ws + (size_t)bh * S * 64);
  const char* vp = (const char*)(vT_ws + (size_t)bh * 64 * S);

  const int t = threadIdx.x, lane = t & 63, w = t >> 6;  // w in [0,8)
  const int l31 = lane & 31, hi = lane >> 5;
  const int swz = (lane & 7) << 4;

  // staging: 512 threads x 16B per tile-half; linear dest t*16, swizzled source
  const int r0 = t >> 3;                               // row 0..63
  const int c0 = ((t & 7) << 4) ^ ((r0 & 7) << 4);

  // Q fragments: Q[q][d = w16*16 + hi*8 + j], pre-scaled by 0.125*log2e
  const char* qrow = qp + (size_t)(qt * 256 + w * 32 + l31) * 128;
  bf16x8 qf[4];
#pragma unroll
  for (int w16 = 0; w16 < 4; ++w16)
    qf[w16] = *(const bf16x8*)(qrow + w16 * 32 + hi * 16);

  f32x16 oA, oB;     // O^T accs: d 0-31 / 32-63 (d = (r&3)+8*(r>>2)+4*hi +32*do2)
#pragma unroll
  for (int r = 0; r < 16; ++r) { oA[r] = 0.f; oB[r] = 0.f; }
  float m_run = -1e30f, l_run = 0.f;

  // prologue: stage tile 0 into buf 0
  gload_lds16(kp + r0 * 128 + c0,  lds[0] + w * 1024 + (lane << 4));
  gload_lds16(vp + r0 * 4096 + c0, lds[0] + 8192 + w * 1024 + (lane << 4));
  __syncthreads();

  for (int tt = 0; tt < 32; ++tt) {
    const int cur = tt & 1;
    const char* Klds = lds[cur];
    const char* Vlds = lds[cur] + 8192;
    if (tt + 1 < 32) {                       // prefetch next tile (2-phase pipeline)
      char* dN = lds[cur ^ 1];
      const int nb = tt + 1;
      gload_lds16(kp + nb * 8192 + r0 * 128 + c0, dN + w * 1024 + (lane << 4));
      gload_lds16(vp + r0 * 4096 + nb * 128 + c0, dN + 8192 + w * 1024 + (lane << 4));
    }

    // QK^T: S^T[kv][q]
    f32x16 sA, sB;
#pragma unroll
    for (int r = 0; r < 16; ++r) { sA[r] = 0.f; sB[r] = 0.f; }
    const char* kb = Klds + l31 * 128;
    __builtin_amdgcn_s_setprio(1);
#pragma unroll
    for (int w16 = 0; w16 < 4; ++w16) {
      const int col = w16 * 32 + hi * 16;
      bf16x8 k0 = *(const bf16x8*)(kb + (col ^ swz));
      bf16x8 k1 = *(const bf16x8*)(kb + 4096 + (col ^ swz));
      sA = __builtin_amdgcn_mfma_f32_32x32x16_bf16(k0, qf[w16], sA, 0, 0, 0);
      sB = __builtin_amdgcn_mfma_f32_32x32x16_bf16(k1, qf[w16], sB, 0, 0, 0);
    }
    __builtin_amdgcn_s_setprio(0);

    // lane-local online softmax (exp2 domain); max via v_max3 fusion
    float mx = fmaxf(sA[0], sA[1]);
#pragma unroll
    for (int r = 2; r < 16; r += 2) mx = fmaxf(fmaxf(mx, sA[r]), sA[r + 1]);
#pragma unroll
    for (int r = 0; r < 16; r += 2) mx = fmaxf(fmaxf(mx, sB[r]), sB[r + 1]);
    mx = fmaxf(mx, __shfl_xor(mx, 32, 64));
    if (__any(mx > m_run + 11.5416f)) {      // defer-max (T13, THR = 8*log2e)
      float nm = fmaxf(m_run, mx);
      float corr = __builtin_amdgcn_exp2f(m_run - nm);
      l_run *= corr;
#pragma unroll
      for (int r = 0; r < 16; ++r) { oA[r] *= corr; oB[r] *= corr; }
      m_run = nm;
    }
    float rs = 0.f;
#pragma unroll
    for (int r = 0; r < 16; ++r) {
      sA[r] = __builtin_amdgcn_exp2f(sA[r] - m_run);
      sB[r] = __builtin_amdgcn_exp2f(sB[r] - m_run);
      rs += sA[r] + sB[r];
    }
    rs += __shfl_xor(rs, 32, 64);
    l_run += rs;

    // P -> bf16 pack + cross-half exchange => PV B-operand fragments
    unsigned pk0[8], pk1[8];
#pragma unroll
    for (int g = 0; g < 4; ++g) {
      pk0[2*g]   = cvtpk(sA[4*g],   sA[4*g+1]);
      pk0[2*g+1] = cvtpk(sA[4*g+2], sA[4*g+3]);
      pk1[2*g]   = cvtpk(sB[4*g],   sB[4*g+1]);
      pk1[2*g+1] = cvtpk(sB[4*g+2], sB[4*g+3]);
    }
    xch4(pk0[0], pk0[1], pk0[2], pk0[3], hi);
    xch4(pk0[4], pk0[5], pk0[6], pk0[7], hi);
    xch4(pk1[0], pk1[1], pk1[2], pk1[3], hi);
    xch4(pk1[4], pk1[5], pk1[6], pk1[7], hi);
    bf16x8 pf[4];
    pf[0] = __builtin_bit_cast(bf16x8, u32x4{pk0[0], pk0[1], pk0[2], pk0[3]});
    pf[1] = __builtin_bit_cast(bf16x8, u32x4{pk0[4], pk0[5], pk0[6], pk0[7]});
    pf[2] = __builtin_bit_cast(bf16x8, u32x4{pk1[0], pk1[1], pk1[2], pk1[3]});
    pf[3] = __builtin_bit_cast(bf16x8, u32x4{pk1[4], pk1[5], pk1[6], pk1[7]});

    // PV: O^T[d][q] += Vt[d][kv] . P[q][kv]
    const char* vb = Vlds + l31 * 128;
    __builtin_amdgcn_s_setprio(1);
#pragma unroll
    for (int ks = 0; ks < 4; ++ks) {
      const int colv = ks * 32 + hi * 16;
      bf16x8 v0 = *(const bf16x8*)(vb + (colv ^ swz));
      bf16x8 v1 = *(const bf16x8*)(vb + 4096 + (colv ^ swz));
      oA = __builtin_amdgcn_mfma_f32_32x32x16_bf16(v0, pf[ks], oA, 0, 0, 0);
      oB = __builtin_amdgcn_mfma_f32_32x32x16_bf16(v1, pf[ks], oB, 0, 0, 0);
    }
    __builtin_amdgcn_s_setprio(0);

    __syncthreads();   // next buf staged + this buf free to overwrite
  }

  // epilogue: normalize, pack to bf16, exchange to d-contiguous runs, 16B stores
  const float inv = 1.f / l_run;
  unsigned ok0[8], ok1[8];
#pragma unroll
  for (int g = 0; g < 4; ++g) {
    ok0[2*g]   = cvtpk(oA[4*g] * inv,   oA[4*g+1] * inv);
    ok0[2*g+1] = cvtpk(oA[4*g+2] * inv, oA[4*g+3] * inv);
    ok1[2*g]   = cvtpk(oB[4*g] * inv,   oB[4*g+1] * inv);
    ok1[2*g+1] = cvtpk(oB[4*g+2] * inv, oB[4*g+3] * inv);
  }
  xch4(ok0[0], ok0[1], ok0[2], ok0[3], hi);
  xch4(ok0[4], ok0[5], ok0[6], ok0[7], hi);
  xch4(ok1[0], ok1[1], ok1[2], ok1[3], hi);
  xch4(ok1[4], ok1[5], ok1[6], ok1[7], hi);

  const int grow = bb * S + qt * 256 + w * 32 + l31;
  ushort_t* orow = attn_bf + (size_t)grow * 1024 + hh * 64;
  *(u32x4*)(orow + 8 * hi)      = u32x4{ok0[0], ok0[1], ok0[2], ok0[3]};
  *(u32x4*)(orow + 16 + 8 * hi) = u32x4{ok0[4], ok0[5], ok0[6], ok0[7]};
  *(u32x4*)(orow + 32 + 8 * hi) = u32x4{ok1[0], ok1[1], ok1[2], ok1[3]};
  *(u32x4*)(orow + 48 + 8 * hi) = u32x4{ok1[4], ok1[5], ok1[6], ok1[7]};
}

// ---------------- residual + layernorm ----------------
__global__ __launch_bounds__(256) void k_ln(const float* __restrict__ z,
                                            const float* __restrict__ x,
                                            const float* __restrict__ lnw,
                                            const float* __restrict__ lnb,
                                            float* __restrict__ out) {
  const int r = blockIdx.x;
  const int t = threadIdx.x, lane = t & 63, w = t >> 6;
  float4 zv = ((const float4*)(z + r * D))[t];
  float4 xv = ((const float4*)(x + r * D))[t];
  float y[4] = {zv.x + xv.x, zv.y + xv.y, zv.z + xv.z, zv.w + xv.w};
  float sum = y[0] + y[1] + y[2] + y[3];
  float sq  = y[0]*y[0] + y[1]*y[1] + y[2]*y[2] + y[3]*y[3];
#pragma unroll
  for (int d = 1; d < 64; d <<= 1) { sum += __shfl_xor(sum, d, 64); sq += __shfl_xor(sq, d, 64); }
  __shared__ float ssum[4], ssq[4];
  if (lane == 0) { ssum[w] = sum; ssq[w] = sq; }
  __syncthreads();
  sum = ssum[0] + ssum[1] + ssum[2] + ssum[3];
  sq  = ssq[0] + ssq[1] + ssq[2] + ssq[3];
  float mean = sum * (1.f / D);
  float var  = sq * (1.f / D) - mean * mean;
  float rstd = rsqrtf(var + 1e-5f);
  float4 wv = ((const float4*)lnw)[t];
  float4 bv = ((const float4*)lnb)[t];
  float4 ov;
  ov.x = (y[0] - mean) * rstd * wv.x + bv.x;
  ov.y = (y[1] - mean) * rstd * wv.y + bv.y;
  ov.z = (y[2] - mean) * rstd * wv.z + bv.z;
  ov.w = (y[3] - mean) * rstd * wv.w + bv.w;
  ((float4*)(out + r * D))[t] = ov;
}

// ---------------- launcher ----------------
extern "C" void kernel_launch(void* const* d_in, const int* in_sizes, int n_in,
                              void* d_out, int out_size, void* d_ws, size_t ws_size,
                              hipStream_t stream) {
  const float* x   = (const float*)d_in[0];
  const float* Wq  = (const float*)d_in[1];
  const float* bq  = (const float*)d_in[2];
  const float* Wk  = (const float*)d_in[3];
  const float* bk  = (const float*)d_in[4];
  const float* Wv  = (const float*)d_in[5];
  const float* bv  = (const float*)d_in[6];
  const float* Wo  = (const float*)d_in[7];
  const float* bo  = (const float*)d_in[8];
  const float* lnw = (const float*)d_in[9];
  const float* lnb = (const float*)d_in[10];

  char* ws = (char*)d_ws;
  ushort_t* xb    = (ushort_t*)(ws + 0);           // 16,777,216
  ushort_t* q_ws  = (ushort_t*)(ws + 16777216);    // 16,777,216
  ushort_t* wt    = (ushort_t*)(ws + 33554432);    //  6,291,456
  ushort_t* wot   = (ushort_t*)(ws + 39845888);    //  2,097,152
  ushort_t* k_ws  = (ushort_t*)(ws + 41943040);    // 16,777,216
  ushort_t* vT_ws = (ushort_t*)(ws + 58720256);    // 16,777,216
  ushort_t* attn  = (ushort_t*)(ws + 75497472);    // 16,777,216  (total 92,274,688)
  float*    z     = (float*)(ws + 0);              // 33,554,432 alias over xb+q_ws

  k_conv_x<<<8192, 256, 0, stream>>>(x, xb);
  k_conv_w<<<768, 256, 0, stream>>>(Wq, Wk, Wv, wt);
  k_conv_wo<<<256, 256, 0, stream>>>(Wo, wot);
  k_qkv_gemm<<<768, 512, 0, stream>>>(xb, wt, bq, bk, bv, q_ws, k_ws, vT_ws);
  k_attn<<<512, 512, 0, stream>>>(q_ws, k_ws, vT_ws, attn);
  k_out_gemm<<<256, 512, 0, stream>>>(attn, wot, bo, z);
  k_ln<<<BS, 256, 0, stream>>>(z, x, lnw, lnb, (float*)d_out);
}

// Round 10
// 288.483 us; speedup vs baseline: 1.3066x; 1.0179x over previous
//
#include <hip/hip_runtime.h>
#include <hip/hip_bf16.h>
#include <stdint.h>

// ---- problem constants ----
constexpr int D  = 1024;
constexpr int H  = 16;
constexpr int DH = 64;
constexpr int B  = 4;
constexpr int S  = 2048;
constexpr int BS = B * S;          // 8192
constexpr int NQKV = 3 * D;        // 3072

typedef __attribute__((ext_vector_type(8))) short bf16x8;
typedef __attribute__((ext_vector_type(4))) float f32x4;
typedef __attribute__((ext_vector_type(16))) float f32x16;
typedef __attribute__((ext_vector_type(4))) unsigned short us4;
typedef __attribute__((ext_vector_type(4))) unsigned int u32x4;
typedef unsigned short ushort_t;

using gu32 = __attribute__((address_space(1))) unsigned int;
using lu32 = __attribute__((address_space(3))) unsigned int;

__device__ __forceinline__ void gload_lds16(const void* g, void* l) {
  __builtin_amdgcn_global_load_lds((gu32*)g, (lu32*)l, 16, 0, 0);
}

__device__ __forceinline__ ushort_t f2bf(float f) {
  uint32_t u = __builtin_bit_cast(uint32_t, f);
  u += 0x7FFFu + ((u >> 16) & 1u);
  return (ushort_t)(u >> 16);
}

// packed f32x2 -> bf16x2 (src0 -> low 16, src1 -> high 16)
__device__ __forceinline__ unsigned cvtpk(float lo, float hi) {
  unsigned r;
  asm("v_cvt_pk_bf16_f32 %0, %1, %2" : "=v"(r) : "v"(lo), "v"(hi));
  return r;
}

// Cross-half exchange: lo-lane keeps w0,w1, gets other half's w0,w1 into w2,w3;
// hi-lane keeps w2,w3 (in place), gets other half's w2,w3 into w0,w1.
__device__ __forceinline__ void xch4(unsigned& w0, unsigned& w1,
                                     unsigned& w2, unsigned& w3, int hi) {
  unsigned sx = hi ? w0 : w2;               // what this lane sends
  unsigned sy = hi ? w1 : w3;
  sx = (unsigned)__shfl_xor((int)sx, 32, 64);
  sy = (unsigned)__shfl_xor((int)sy, 32, 64);
  if (hi) { w0 = sx; w1 = sy; } else { w2 = sx; w3 = sy; }
}

// ---------------- merged conversion kernel (one dispatch) ----------------
// grid 9216 = [0,8192) conv_x | [8192,8960) conv_w | [8960,9216) conv_wo
__global__ __launch_bounds__(256) void k_conv_all(const float* __restrict__ x,
                                                  const float* __restrict__ Wq,
                                                  const float* __restrict__ Wk,
                                                  const float* __restrict__ Wv,
                                                  const float* __restrict__ Wo,
                                                  ushort_t* __restrict__ xb,
                                                  ushort_t* __restrict__ wt,
                                                  ushort_t* __restrict__ wot) {
  __shared__ ushort_t tile[64][65];
  const int bid = blockIdx.x;
  const int t = threadIdx.x;
  if (bid < 8192) {
    int i = (bid * 256 + t) * 4;
    float4 v = *(const float4*)(x + i);
    us4 o;
    o[0] = f2bf(v.x); o[1] = f2bf(v.y); o[2] = f2bf(v.z); o[3] = f2bf(v.w);
    *(us4*)(xb + i) = o;
    return;
  }
  const float* src;
  ushort_t* dstbase;
  int d0, rowbase;
  if (bid < 8960) {             // conv_w: 768 blocks = which(3) x h(16) x dblk(16)
    int b = bid - 8192;
    int which = b >> 8, hh = (b >> 4) & 15;
    d0 = (b & 15) * 64;
    src = ((which == 0) ? Wq : (which == 1) ? Wk : Wv) + (size_t)hh * D * DH;
    dstbase = wt;
    rowbase = which * 1024 + hh * 64;
  } else {                      // conv_wo: 256 blocks = cblk(16) x dblk(16)
    int b = bid - 8960;
    int c0 = (b >> 4) * 64;
    d0 = (b & 15) * 64;
    src = Wo + c0;              // row d reads Wo[d][c0+e] with row stride 1024
    dstbase = wot;
    rowbase = c0;
  }
  const int rstride = (bid < 8960) ? DH : 1024;
  const int dd = t >> 4, e4 = (t & 15) * 4;
#pragma unroll
  for (int p = 0; p < 4; ++p) {
    int d = dd + p * 16;
    float4 v = *(const float4*)(src + (size_t)(d0 + d) * rstride + e4);
    tile[e4 + 0][d] = f2bf(v.x);
    tile[e4 + 1][d] = f2bf(v.y);
    tile[e4 + 2][d] = f2bf(v.z);
    tile[e4 + 3][d] = f2bf(v.w);
  }
  __syncthreads();
  const int e = t >> 2, dp = (t & 3) * 16;
  ushort_t* dst = dstbase + (size_t)(rowbase + e) * 1024 + d0 + dp;
  us4 o[4];
#pragma unroll
  for (int g = 0; g < 4; ++g)
#pragma unroll
    for (int j = 0; j < 4; ++j) o[g][j] = tile[e][dp + g * 4 + j];
#pragma unroll
  for (int g = 0; g < 4; ++g) *(us4*)(dst + g * 4) = o[g];
}

// ---- GEMM core: BM=256 x BN=128, BK=32, 8 waves (4M x 2N), 3-buffer counted vmcnt ----
__device__ __forceinline__ void gemm_core_256x128(const ushort_t* __restrict__ A,
                                                  const ushort_t* __restrict__ Bt,
                                                  int m0, int n0,
                                                  f32x4 acc[4][4], char* lds) {
  const int t = threadIdx.x;
  const int lane = t & 63, w = t >> 6;
  const int wm = w >> 1, wn = w & 1;
  const int lrow = lane & 15;
  const int chx = (((lane >> 4) ^ ((lrow >> 1) & 3)) << 4);

#pragma unroll
  for (int mi = 0; mi < 4; mi++)
#pragma unroll
    for (int ni = 0; ni < 4; ni++) acc[mi][ni] = f32x4{0.f, 0.f, 0.f, 0.f};

  const int prow = t >> 2;
  const int sw16 = (((t & 3) ^ ((prow >> 1) & 3)) << 4);
  const char* sA0 = (const char*)A  + (size_t)(m0 + prow) * 2048 + sw16;
  const char* sB0 = (const char*)Bt + (size_t)(n0 + prow) * 2048 + sw16;

  auto STAGE = [&](int kt) {
    char* bb = lds + (kt % 3) * 24576;
    const size_t ko = (size_t)kt * 64;
    gload_lds16(sA0 + ko,              bb + w * 1024);
    gload_lds16(sA0 + 128 * 2048 + ko, bb + 8192 + w * 1024);
    gload_lds16(sB0 + ko,              bb + 16384 + w * 1024);
  };

  STAGE(0); STAGE(1);

  for (int kt = 0; kt < 32; ++kt) {
    if (kt < 31) asm volatile("s_waitcnt vmcnt(3)" ::: "memory");
    else         asm volatile("s_waitcnt vmcnt(0)" ::: "memory");
    __builtin_amdgcn_sched_barrier(0);
    __builtin_amdgcn_s_barrier();
    __builtin_amdgcn_sched_barrier(0);
    if (kt + 2 < 32) STAGE(kt + 2);
    const char* bb = lds + (kt % 3) * 24576;
    const char* aB = bb + wm * 4096 + lrow * 64 + chx;
    const char* bB = bb + 16384 + wn * 4096 + lrow * 64 + chx;
    bf16x8 af[4], bf[4];
#pragma unroll
    for (int mi = 0; mi < 4; mi++) af[mi] = *(const bf16x8*)(aB + mi * 1024);
#pragma unroll
    for (int ni = 0; ni < 4; ni++) bf[ni] = *(const bf16x8*)(bB + ni * 1024);
    __builtin_amdgcn_s_setprio(1);
#pragma unroll
    for (int mi = 0; mi < 4; mi++)
#pragma unroll
      for (int ni = 0; ni < 4; ni++)
        acc[mi][ni] = __builtin_amdgcn_mfma_f32_16x16x32_bf16(af[mi], bf[ni], acc[mi][ni], 0, 0, 0);
    __builtin_amdgcn_s_setprio(0);
  }
}

// QKV GEMM: grid 768 (3 clean rounds), XCD-swizzled; bias + scatter epilogue
__global__ __launch_bounds__(512, 2) void k_qkv_gemm(const ushort_t* __restrict__ xb,
                                                     const ushort_t* __restrict__ wt,
                                                     const float* __restrict__ bq,
                                                     const float* __restrict__ bk,
                                                     const float* __restrict__ bv,
                                                     ushort_t* __restrict__ q_ws,
                                                     ushort_t* __restrict__ k_ws,
                                                     ushort_t* __restrict__ vT_ws) {
  __shared__ __align__(16) char lds[3][24576];
  const int bid = blockIdx.x;
  const int wg = (bid & 7) * 96 + (bid >> 3);
  const int tm = wg / 24, tn = wg - tm * 24;
  const int m0 = tm * 256, n0 = tn * 128;
  f32x4 acc[4][4];
  gemm_core_256x128(xb, wt, m0, n0, acc, &lds[0][0]);

  constexpr float QSC = 0.18033688011112042f;   // 0.125 * log2(e)
  const int t = threadIdx.x, lane = t & 63, w = t >> 6;
  const int wm = w >> 1, wn = w & 1;
  const int lrow = lane & 15, lgrp = lane >> 4;
#pragma unroll
  for (int mi = 0; mi < 4; mi++) {
    int rbase = m0 + wm * 64 + mi * 16 + lgrp * 4;
    int bb = rbase >> 11, ss0 = rbase & 2047;
#pragma unroll
    for (int ni = 0; ni < 4; ni++) {
      int c = n0 + wn * 64 + ni * 16 + lrow;
      int which = c >> 10, cl = c & 1023;
      int hh = cl >> 6, e = cl & 63;
      if (which == 0) {
        float bias = bq[cl];
#pragma unroll
        for (int i = 0; i < 4; i++)
          q_ws[((bb * H + hh) * S + ss0 + i) * 64 + e] = f2bf((acc[mi][ni][i] + bias) * QSC);
      } else if (which == 1) {
        float bias = bk[cl];
#pragma unroll
        for (int i = 0; i < 4; i++)
          k_ws[((bb * H + hh) * S + ss0 + i) * 64 + e] = f2bf(acc[mi][ni][i] + bias);
      } else {
        float bias = bv[cl];
        us4 pv;
#pragma unroll
        for (int i = 0; i < 4; i++) pv[i] = f2bf(acc[mi][ni][i] + bias);
        *(us4*)(vT_ws + (size_t)((bb * H + hh) * 64 + e) * S + ss0) = pv;
      }
    }
  }
}

// Output GEMM: grid 256 (exactly 1/CU); z = acc + bo + x (residual fused, fp32)
__global__ __launch_bounds__(512, 2) void k_out_gemm(const ushort_t* __restrict__ attn_bf,
                                                     const ushort_t* __restrict__ wot,
                                                     const float* __restrict__ bo,
                                                     const float* __restrict__ xres,
                                                     float* __restrict__ z) {
  __shared__ __align__(16) char lds[3][24576];
  const int bid = blockIdx.x;
  const int wg = (bid & 7) * 32 + (bid >> 3);
  const int tm = wg >> 3, tn = wg & 7;
  const int m0 = tm * 256, n0 = tn * 128;
  f32x4 acc[4][4];
  gemm_core_256x128(attn_bf, wot, m0, n0, acc, &lds[0][0]);

  const int t = threadIdx.x, lane = t & 63, w = t >> 6;
  const int wm = w >> 1, wn = w & 1;
  const int lrow = lane & 15, lgrp = lane >> 4;
#pragma unroll
  for (int mi = 0; mi < 4; mi++) {
    int rbase = m0 + wm * 64 + mi * 16 + lgrp * 4;
#pragma unroll
    for (int ni = 0; ni < 4; ni++) {
      int c = n0 + wn * 64 + ni * 16 + lrow;
#pragma unroll
      for (int i = 0; i < 4; i++) {
        size_t idx = (size_t)(rbase + i) * D + c;
        z[idx] = acc[mi][ni][i] + bo[c] + xres[idx];
      }
    }
  }
}

// ---------------- flash attention: QBLK=256, 8 waves, KVBLK=128 phases ----------------
// grid 512 = 64 bh x 8 q-tiles of 256 rows. 16 phases, each stages 2 kv-64 tiles
// (buffers 2 x 32KB: K0|K1|V0|V1 of 8KB each) -> 16 barriers instead of 32.
__global__ __launch_bounds__(512, 4) void k_attn(const ushort_t* __restrict__ q_ws,
                                                 const ushort_t* __restrict__ k_ws,
                                                 const ushort_t* __restrict__ vT_ws,
                                                 ushort_t* __restrict__ attn_bf) {
  __shared__ __align__(16) char lds[2][32768];
  const int bid = blockIdx.x;                    // 512 blocks
  const int bh = ((bid & 7) << 3) | (bid >> 6);  // XCD swizzle, bijective
  const int qt = (bid >> 3) & 7;
  const int bb = bh >> 4, hh = bh & 15;
  const char* qp = (const char*)(q_ws + (size_t)bh * S * 64);
  const char* kp = (const char*)(k_ws + (size_t)bh * S * 64);
  const char* vp = (const char*)(vT_ws + (size_t)bh * 64 * S);

  const int t = threadIdx.x, lane = t & 63, w = t >> 6;  // w in [0,8)
  const int l31 = lane & 31, hi = lane >> 5;
  const int swz = (lane & 7) << 4;

  // staging: 512 threads x 16B covers one 8KB kv-64 subtile; linear dest t*16,
  // swizzled source (row = t>>3 in [0,64), col = ((t&7)<<4) ^ ((row&7)<<4))
  const int r0 = t >> 3;
  const int c0 = ((t & 7) << 4) ^ ((r0 & 7) << 4);
  const int dst16 = t << 4;

  // Q fragments: Q[q][d = w16*16 + hi*8 + j], pre-scaled by 0.125*log2e
  const char* qrow = qp + (size_t)(qt * 256 + w * 32 + l31) * 128;
  bf16x8 qf[4];
#pragma unroll
  for (int w16 = 0; w16 < 4; ++w16)
    qf[w16] = *(const bf16x8*)(qrow + w16 * 32 + hi * 16);

  f32x16 oA, oB;     // O^T accs: d 0-31 / 32-63
#pragma unroll
  for (int r = 0; r < 16; ++r) { oA[r] = 0.f; oB[r] = 0.f; }
  float m_run = -1e30f, l_run = 0.f;

  // prologue: stage kv-tiles 0,1 into buf 0
#pragma unroll
  for (int j = 0; j < 2; ++j) {
    gload_lds16(kp + j * 8192 + r0 * 128 + c0,  lds[0] + j * 8192 + dst16);
    gload_lds16(vp + r0 * 4096 + j * 128 + c0,  lds[0] + 16384 + j * 8192 + dst16);
  }
  __syncthreads();

  for (int ph = 0; ph < 16; ++ph) {
    const int cur = ph & 1;
    if (ph + 1 < 16) {                       // prefetch next phase's 2 kv-tiles
      char* dN = lds[cur ^ 1];
      const int nb0 = (ph + 1) * 2;
#pragma unroll
      for (int j = 0; j < 2; ++j) {
        gload_lds16(kp + (size_t)(nb0 + j) * 8192 + r0 * 128 + c0, dN + j * 8192 + dst16);
        gload_lds16(vp + r0 * 4096 + (nb0 + j) * 128 + c0, dN + 16384 + j * 8192 + dst16);
      }
    }

#pragma unroll
    for (int sub = 0; sub < 2; ++sub) {
      const char* Klds = lds[cur] + sub * 8192;
      const char* Vlds = lds[cur] + 16384 + sub * 8192;

      // QK^T: S^T[kv][q]
      f32x16 sA, sB;
#pragma unroll
      for (int r = 0; r < 16; ++r) { sA[r] = 0.f; sB[r] = 0.f; }
      const char* kb = Klds + l31 * 128;
      __builtin_amdgcn_s_setprio(1);
#pragma unroll
      for (int w16 = 0; w16 < 4; ++w16) {
        const int col = w16 * 32 + hi * 16;
        bf16x8 k0 = *(const bf16x8*)(kb + (col ^ swz));
        bf16x8 k1 = *(const bf16x8*)(kb + 4096 + (col ^ swz));
        sA = __builtin_amdgcn_mfma_f32_32x32x16_bf16(k0, qf[w16], sA, 0, 0, 0);
        sB = __builtin_amdgcn_mfma_f32_32x32x16_bf16(k1, qf[w16], sB, 0, 0, 0);
      }
      __builtin_amdgcn_s_setprio(0);

      // lane-local online softmax (exp2 domain)
      float mx = fmaxf(sA[0], sA[1]);
#pragma unroll
      for (int r = 2; r < 16; r += 2) mx = fmaxf(fmaxf(mx, sA[r]), sA[r + 1]);
#pragma unroll
      for (int r = 0; r < 16; r += 2) mx = fmaxf(fmaxf(mx, sB[r]), sB[r + 1]);
      mx = fmaxf(mx, __shfl_xor(mx, 32, 64));
      if (__any(mx > m_run + 11.5416f)) {    // defer-max (THR = 8*log2e)
        float nm = fmaxf(m_run, mx);
        float corr = __builtin_amdgcn_exp2f(m_run - nm);
        l_run *= corr;
#pragma unroll
        for (int r = 0; r < 16; ++r) { oA[r] *= corr; oB[r] *= corr; }
        m_run = nm;
      }
      float rs = 0.f;
#pragma unroll
      for (int r = 0; r < 16; ++r) {
        sA[r] = __builtin_amdgcn_exp2f(sA[r] - m_run);
        sB[r] = __builtin_amdgcn_exp2f(sB[r] - m_run);
        rs += sA[r] + sB[r];
      }
      rs += __shfl_xor(rs, 32, 64);
      l_run += rs;

      // P -> bf16 pack + cross-half exchange => PV B-operand fragments
      unsigned pk0[8], pk1[8];
#pragma unroll
      for (int g = 0; g < 4; ++g) {
        pk0[2*g]   = cvtpk(sA[4*g],   sA[4*g+1]);
        pk0[2*g+1] = cvtpk(sA[4*g+2], sA[4*g+3]);
        pk1[2*g]   = cvtpk(sB[4*g],   sB[4*g+1]);
        pk1[2*g+1] = cvtpk(sB[4*g+2], sB[4*g+3]);
      }
      xch4(pk0[0], pk0[1], pk0[2], pk0[3], hi);
      xch4(pk0[4], pk0[5], pk0[6], pk0[7], hi);
      xch4(pk1[0], pk1[1], pk1[2], pk1[3], hi);
      xch4(pk1[4], pk1[5], pk1[6], pk1[7], hi);
      bf16x8 pf[4];
      pf[0] = __builtin_bit_cast(bf16x8, u32x4{pk0[0], pk0[1], pk0[2], pk0[3]});
      pf[1] = __builtin_bit_cast(bf16x8, u32x4{pk0[4], pk0[5], pk0[6], pk0[7]});
      pf[2] = __builtin_bit_cast(bf16x8, u32x4{pk1[0], pk1[1], pk1[2], pk1[3]});
      pf[3] = __builtin_bit_cast(bf16x8, u32x4{pk1[4], pk1[5], pk1[6], pk1[7]});

      // PV: O^T[d][q] += Vt[d][kv] . P[q][kv]
      const char* vb = Vlds + l31 * 128;
      __builtin_amdgcn_s_setprio(1);
#pragma unroll
      for (int ks = 0; ks < 4; ++ks) {
        const int colv = ks * 32 + hi * 16;
        bf16x8 v0 = *(const bf16x8*)(vb + (colv ^ swz));
        bf16x8 v1 = *(const bf16x8*)(vb + 4096 + (colv ^ swz));
        oA = __builtin_amdgcn_mfma_f32_32x32x16_bf16(v0, pf[ks], oA, 0, 0, 0);
        oB = __builtin_amdgcn_mfma_f32_32x32x16_bf16(v1, pf[ks], oB, 0, 0, 0);
      }
      __builtin_amdgcn_s_setprio(0);
    }

    __syncthreads();   // next buf fully staged + this buf free to overwrite
  }

  // epilogue: normalize, pack to bf16, exchange to d-contiguous runs, 16B stores
  const float inv = 1.f / l_run;
  unsigned ok0[8], ok1[8];
#pragma unroll
  for (int g = 0; g < 4; ++g) {
    ok0[2*g]   = cvtpk(oA[4*g] * inv,   oA[4*g+1] * inv);
    ok0[2*g+1] = cvtpk(oA[4*g+2] * inv, oA[4*g+3] * inv);
    ok1[2*g]   = cvtpk(oB[4*g] * inv,   oB[4*g+1] * inv);
    ok1[2*g+1] = cvtpk(oB[4*g+2] * inv, oB[4*g+3] * inv);
  }
  xch4(ok0[0], ok0[1], ok0[2], ok0[3], hi);
  xch4(ok0[4], ok0[5], ok0[6], ok0[7], hi);
  xch4(ok1[0], ok1[1], ok1[2], ok1[3], hi);
  xch4(ok1[4], ok1[5], ok1[6], ok1[7], hi);

  const int grow = bb * S + qt * 256 + w * 32 + l31;
  ushort_t* orow = attn_bf + (size_t)grow * 1024 + hh * 64;
  *(u32x4*)(orow + 8 * hi)      = u32x4{ok0[0], ok0[1], ok0[2], ok0[3]};
  *(u32x4*)(orow + 16 + 8 * hi) = u32x4{ok0[4], ok0[5], ok0[6], ok0[7]};
  *(u32x4*)(orow + 32 + 8 * hi) = u32x4{ok1[0], ok1[1], ok1[2], ok1[3]};
  *(u32x4*)(orow + 48 + 8 * hi) = u32x4{ok1[4], ok1[5], ok1[6], ok1[7]};
}

// ---------------- layernorm (residual already folded into z) ----------------
__global__ __launch_bounds__(256) void k_ln(const float* __restrict__ z,
                                            const float* __restrict__ lnw,
                                            const float* __restrict__ lnb,
                                            float* __restrict__ out) {
  const int r = blockIdx.x;
  const int t = threadIdx.x, lane = t & 63, w = t >> 6;
  float4 zv = ((const float4*)(z + r * D))[t];
  float y[4] = {zv.x, zv.y, zv.z, zv.w};
  float sum = y[0] + y[1] + y[2] + y[3];
  float sq  = y[0]*y[0] + y[1]*y[1] + y[2]*y[2] + y[3]*y[3];
#pragma unroll
  for (int d = 1; d < 64; d <<= 1) { sum += __shfl_xor(sum, d, 64); sq += __shfl_xor(sq, d, 64); }
  __shared__ float ssum[4], ssq[4];
  if (lane == 0) { ssum[w] = sum; ssq[w] = sq; }
  __syncthreads();
  sum = ssum[0] + ssum[1] + ssum[2] + ssum[3];
  sq  = ssq[0] + ssq[1] + ssq[2] + ssq[3];
  float mean = sum * (1.f / D);
  float var  = sq * (1.f / D) - mean * mean;
  float rstd = rsqrtf(var + 1e-5f);
  float4 wv = ((const float4*)lnw)[t];
  float4 bv = ((const float4*)lnb)[t];
  float4 ov;
  ov.x = (y[0] - mean) * rstd * wv.x + bv.x;
  ov.y = (y[1] - mean) * rstd * wv.y + bv.y;
  ov.z = (y[2] - mean) * rstd * wv.z + bv.z;
  ov.w = (y[3] - mean) * rstd * wv.w + bv.w;
  ((float4*)(out + r * D))[t] = ov;
}

// ---------------- launcher ----------------
extern "C" void kernel_launch(void* const* d_in, const int* in_sizes, int n_in,
                              void* d_out, int out_size, void* d_ws, size_t ws_size,
                              hipStream_t stream) {
  const float* x   = (const float*)d_in[0];
  const float* Wq  = (const float*)d_in[1];
  const float* bq  = (const float*)d_in[2];
  const float* Wk  = (const float*)d_in[3];
  const float* bk  = (const float*)d_in[4];
  const float* Wv  = (const float*)d_in[5];
  const float* bv  = (const float*)d_in[6];
  const float* Wo  = (const float*)d_in[7];
  const float* bo  = (const float*)d_in[8];
  const float* lnw = (const float*)d_in[9];
  const float* lnb = (const float*)d_in[10];

  char* ws = (char*)d_ws;
  ushort_t* xb    = (ushort_t*)(ws + 0);           // 16,777,216
  ushort_t* q_ws  = (ushort_t*)(ws + 16777216);    // 16,777,216
  ushort_t* wt    = (ushort_t*)(ws + 33554432);    //  6,291,456
  ushort_t* wot   = (ushort_t*)(ws + 39845888);    //  2,097,152
  ushort_t* k_ws  = (ushort_t*)(ws + 41943040);    // 16,777,216
  ushort_t* vT_ws = (ushort_t*)(ws + 58720256);    // 16,777,216
  ushort_t* attn  = (ushort_t*)(ws + 75497472);    // 16,777,216  (total 92,274,688)
  float*    z     = (float*)(ws + 0);              // 33,554,432 alias over xb+q_ws

  k_conv_all<<<9216, 256, 0, stream>>>(x, Wq, Wk, Wv, Wo, xb, wt, wot);
  k_qkv_gemm<<<768, 512, 0, stream>>>(xb, wt, bq, bk, bv, q_ws, k_ws, vT_ws);
  k_attn<<<512, 512, 0, stream>>>(q_ws, k_ws, vT_ws, attn);
  k_out_gemm<<<256, 512, 0, stream>>>(attn, wot, bo, x, z);
  k_ln<<<BS, 256, 0, stream>>>(z, lnw, lnb, (float*)d_out);
}